// Round 17
// baseline (407.588 us; speedup 1.0000x reference)
//
#include <hip/hip_runtime.h>
#include <hip/hip_bf16.h>
#include <math.h>

#define B_SZ    32
#define LSEQ    1024
#define DIN     128
#define HDIM    256
#define NLAYERS 4
#define NSTATE  32
#define DOUT    10
#define M_ROWS  (B_SZ*LSEQ)   // 32768
#define CH      64            // scan chunk length
#define NCH     (LSEQ/CH)     // 16 chunks
#define NBC     (B_SZ*NCH)    // 512 chunk-columns

typedef __hip_bfloat16 bf16;
typedef __attribute__((ext_vector_type(8))) short bf16x8;
typedef __attribute__((ext_vector_type(4))) float f32x4;

__device__ __forceinline__ unsigned short f2bu(float x) {
    bf16 b = __float2bfloat16(x);
    return *(unsigned short*)&b;
}
__device__ __forceinline__ float bu2f(unsigned short u) {
    bf16 b = *(bf16*)&u;
    return __bfloat162float(b);
}

// inline S4D discretization: returns (dtAre, dtAim, Wre, Wim)
__device__ __forceinline__ float4 s4param(const float* __restrict__ log_dt,
                                          const float* __restrict__ A_re_log,
                                          const float* __restrict__ A_im,
                                          const float* __restrict__ B_re,
                                          const float* __restrict__ B_im,
                                          const float* __restrict__ C_re,
                                          const float* __restrict__ C_im,
                                          int layer, int h, int n) {
    int hn = layer * HDIM + h;
    int idx = hn * NSTATE + n;
    float dt   = expf(log_dt[hn]);
    float Are  = -expf(A_re_log[idx]);
    float Aim  = A_im[idx];
    float dtAre = dt * Are, dtAim = dt * Aim;
    float ea   = expf(dtAre);
    float dAre = ea * cosf(dtAim), dAim = ea * sinf(dtAim);
    float nre = dAre - 1.0f, nim = dAim;
    float inv = 1.0f / (Are * Are + Aim * Aim);
    float tre = (nre * Are + nim * Aim) * inv;
    float tim = (nim * Are - nre * Aim) * inv;
    float Brv = B_re[idx], Biv = B_im[idx];
    float dBre = Brv * tre - Biv * tim;
    float dBim = Brv * tim + Biv * tre;
    float Crv = C_re[idx], Civ = C_im[idx];
    float Wre = Crv * dBre - Civ * dBim;
    float Wim = Crv * dBim + Civ * dBre;
    return make_float4(dtAre, dtAim, Wre, Wim);
}

// ---------------- ONE setup kernel: V/M, Td, PA64, weight transposes ----------------
#define VMB_ (NLAYERS*HDIM*64*32/256)   // 32768
#define TDB_ ((NLAYERS*HDIM*66+255)/256) // 264
#define PAB_ (NLAYERS*NSTATE*HDIM/256)  // 128
#define WCB_ (NLAYERS*512*256/256)      // 2048
__global__ void k_setup(const float* __restrict__ log_dt, const float* __restrict__ A_re_log,
                        const float* __restrict__ A_im, const float* __restrict__ B_re,
                        const float* __restrict__ B_im, const float* __restrict__ C_re,
                        const float* __restrict__ C_im, const float* __restrict__ out_w,
                        const float* __restrict__ enc_w, float* __restrict__ Td,
                        bf16* __restrict__ Vg, bf16* __restrict__ Mg,
                        float2* __restrict__ PA64, bf16* __restrict__ Wt,
                        bf16* __restrict__ Wet) {
    const float inv2pi = 0.15915494309189535f;
    const float twopi  = 6.283185307179586f;
    int bx = blockIdx.x;
    if (bx < VMB_) {                                 // V/M pair-elements
        int gid = bx * 256 + threadIdx.x;
        int jp = (gid & 31) * 2;
        int row = gid >> 5;                          // ((layer*256+h)*64)+comp
        int comp = row & 63, h = (row >> 6) & 255, layer = row >> 14;
        int n = comp >> 1, isIm = comp & 1;
        float4 q = s4param(log_dt, A_re_log, A_im, B_re, B_im, C_re, C_im, layer, h, n);
        unsigned int vpk = 0, mpk = 0;
#pragma unroll
        for (int e = 0; e < 2; ++e) {
            int j = jp + e;
            float dv = (float)(63 - j);
            float magv = __expf(dv * q.x);
            float pr = dv * q.y * inv2pi;
            float th = (pr - floorf(pr)) * twopi;
            float c = __cosf(th), s = __sinf(th);
            float vre = magv * (q.z * c - q.w * s);
            float vim = magv * (q.z * s + q.w * c);
            vpk |= (unsigned int)f2bu(isIm ? vim : vre) << (16 * e);
            float dm = (float)(j + 1);
            float magm = __expf(dm * q.x);
            float pr2 = dm * q.y * inv2pi;
            float th2 = (pr2 - floorf(pr2)) * twopi;
            float mv = isIm ? (-2.f * magm * __sinf(th2)) : (2.f * magm * __cosf(th2));
            mpk |= (unsigned int)f2bu(mv) << (16 * e);
        }
        ((unsigned int*)Vg)[(size_t)row * 32 + (jp >> 1)] = vpk;
        ((unsigned int*)Mg)[(size_t)row * 32 + (jp >> 1)] = mpk;
    } else if (bx < VMB_ + TDB_) {                   // Td
        int gid = (bx - VMB_) * 256 + threadIdx.x;
        int d = gid % 66;
        int lh = gid / 66;
        if (lh < NLAYERS * HDIM && d < 65) {
            int layer = lh >> 8, h = lh & 255;
            float fd = (float)d;
            float acc = 0.f;
            for (int n = 0; n < NSTATE; ++n) {
                float4 q = s4param(log_dt, A_re_log, A_im, B_re, B_im, C_re, C_im, layer, h, n);
                float mag = __expf(fd * q.x);
                float pr = fd * q.y * inv2pi;
                float th = (pr - floorf(pr)) * twopi;
                acc += mag * (q.z * __cosf(th) - q.w * __sinf(th));
            }
            Td[(size_t)lh * 66 + d] = 2.f * acc;
        }
    } else if (bx < VMB_ + TDB_ + PAB_) {            // PA64 = dA^64 per (layer,n,h)
        int idx = (bx - VMB_ - TDB_) * 256 + threadIdx.x;
        int h = idx & 255, n = (idx >> 8) & 31, layer = idx >> 13;
        float4 q = s4param(log_dt, A_re_log, A_im, B_re, B_im, C_re, C_im, layer, h, n);
        float e64 = expf(64.0f * q.x);
        float ph  = 64.0f * q.y;
        PA64[idx] = make_float2(e64 * cosf(ph), e64 * sinf(ph));
    } else if (bx < VMB_ + TDB_ + PAB_ + WCB_) {     // Wt transpose
        int idx = (bx - VMB_ - TDB_ - PAB_) * 256 + threadIdx.x;
        int k = idx & 255;
        int n = (idx >> 8) & 511;
        int layer = idx >> 17;
        Wt[idx] = __float2bfloat16(out_w[((size_t)(layer * 256 + k)) * 512 + n]);
    } else {                                         // Wet transpose
        int idx = (bx - VMB_ - TDB_ - PAB_ - WCB_) * 256 + threadIdx.x;
        int k = idx & 127, n = idx >> 7;
        Wet[idx] = __float2bfloat16(enc_w[(size_t)k * HDIM + n]);
    }
}

// ---------------- encoder GEMM (bf16 MFMA): H = X@We + b, + transposed Ut output ----------------
__global__ __launch_bounds__(256) void k_enc2(const float* __restrict__ X, const bf16* __restrict__ Wet,
                                              const float* __restrict__ bias, float* __restrict__ H,
                                              bf16* __restrict__ Ut) {
    __shared__ bf16 A_s[128 * 136];
    __shared__ bf16 B_s[64 * 136];
    int tid = threadIdx.x;
    int lane = tid & 63, wv = tid >> 6, quad = lane >> 4, fr = lane & 15;
    int m0 = blockIdx.x * 128, n0 = blockIdx.y * 64;
#pragma unroll
    for (int i = 0; i < 16; ++i) {               // stage X fp32 -> bf16 [m][k]
        int q = tid + i * 256, row = q >> 5, seg = q & 31;
        float4 v = *(const float4*)&X[(size_t)(m0 + row) * DIN + seg * 4];
        bf16* dst = &A_s[row * 136 + seg * 4];
        dst[0] = __float2bfloat16(v.x); dst[1] = __float2bfloat16(v.y);
        dst[2] = __float2bfloat16(v.z); dst[3] = __float2bfloat16(v.w);
    }
#pragma unroll
    for (int i = 0; i < 4; ++i) {                // stage Wet [n][k]
        int q = tid + i * 256, row = q >> 4, seg = q & 15;
        *(uint4*)&B_s[row * 136 + seg * 8] = *(const uint4*)&Wet[(size_t)(n0 + row) * DIN + seg * 8];
    }
    __syncthreads();
    f32x4 acc[2][4];
#pragma unroll
    for (int mt = 0; mt < 2; ++mt)
#pragma unroll
        for (int nt = 0; nt < 4; ++nt) acc[mt][nt] = (f32x4){0.f, 0.f, 0.f, 0.f};
#pragma unroll
    for (int ks = 0; ks < 4; ++ks) {
        bf16x8 a[2], b[4];
#pragma unroll
        for (int mt = 0; mt < 2; ++mt)
            a[mt] = *(const bf16x8*)&A_s[(wv * 32 + mt * 16 + fr) * 136 + ks * 32 + quad * 8];
#pragma unroll
        for (int nt = 0; nt < 4; ++nt)
            b[nt] = *(const bf16x8*)&B_s[(nt * 16 + fr) * 136 + ks * 32 + quad * 8];
#pragma unroll
        for (int mt = 0; mt < 2; ++mt)
#pragma unroll
            for (int nt = 0; nt < 4; ++nt)
                acc[mt][nt] = __builtin_amdgcn_mfma_f32_16x16x32_bf16(a[mt], b[nt], acc[mt][nt], 0, 0, 0);
    }
    __syncthreads();                             // B_s reuse as transpose bounce
#pragma unroll
    for (int mt = 0; mt < 2; ++mt)
#pragma unroll
        for (int nt = 0; nt < 4; ++nt) {
            int n = n0 + nt * 16 + fr;
            float bv = bias[n];
#pragma unroll
            for (int r = 0; r < 4; ++r) {
                int m = m0 + wv * 32 + mt * 16 + quad * 4 + r;
                float hv = acc[mt][nt][r] + bv;
                H[(size_t)m * HDIM + n] = hv;
                B_s[(nt * 16 + fr) * 136 + (wv * 32 + mt * 16 + quad * 4 + r)] = __float2bfloat16(hv);
            }
        }
    __syncthreads();
#pragma unroll
    for (int i = 0; i < 4; ++i) {                // coalesced Ut store [h][m]
        int q = tid + i * 256, row = q >> 4, seg = q & 15;
        *(uint4*)&Ut[(size_t)(n0 + row) * M_ROWS + m0 + seg * 8] = *(uint4*)&B_s[row * 136 + seg * 8];
    }
}

// ---------------- fused conv: E-MFMA + in-LDS carry scan + T|M-MFMA + GELU ----------------
__global__ __launch_bounds__(256) void k_conv(const bf16* __restrict__ Ut,
                                              const bf16* __restrict__ Vg,
                                              const bf16* __restrict__ Mg,
                                              const float* __restrict__ Tdl,
                                              const float2* __restrict__ PA,
                                              const float* __restrict__ Dw,
                                              bf16* __restrict__ Yt) {
    __shared__ bf16 u_s[128 * 72];               // [bc][j]
    __shared__ bf16 A_s[64 * 136];               // [l][k2], k2<64: T, k2>=64: M
    __shared__ bf16 Eo_s[128 * 72];              // [bc][comp] E bounce; reused as o_s
    __shared__ bf16 c_s[128 * 72];               // [bc][comp] carries
    __shared__ float Td_s[65];
    int h = blockIdx.x, bc0 = blockIdx.y * 128;
    int tid = threadIdx.x;
    int lane = tid & 63, wv = tid >> 6, quad = lane >> 4, fr = lane & 15;
    if (tid < 65) Td_s[tid] = Tdl[(size_t)h * 66 + tid];
#pragma unroll
    for (int i = 0; i < 2; ++i) {                // stage M transposed into A_s cols 64..127
        int q = tid + i * 256, comp = q >> 3, seg = q & 7;
        uint4 v = *(const uint4*)&Mg[((size_t)h * 64 + comp) * 64 + seg * 8];
        const bf16* pv = (const bf16*)&v;
#pragma unroll
        for (int e = 0; e < 8; ++e) A_s[(seg * 8 + e) * 136 + 64 + comp] = pv[e];
    }
#pragma unroll
    for (int i = 0; i < 4; ++i) {                // stage u tile
        int q = tid + i * 256, row = q >> 3, c8 = q & 7;
        *(uint4*)&u_s[row * 72 + c8 * 8] =
            *(const uint4*)&Ut[(size_t)h * M_ROWS + (size_t)(bc0 + row) * 64 + c8 * 8];
    }
    __syncthreads();                             // u_s + Td_s ready
#pragma unroll
    for (int i = 0; i < 16; ++i) {               // Toeplitz T fill
        int q = tid + i * 256, l = q >> 6, j = q & 63, d = l - j;
        A_s[l * 136 + j] = __float2bfloat16(d >= 0 ? Td_s[d] : 0.f);
    }
    f32x4 eacc[4][2];
#pragma unroll
    for (int mt = 0; mt < 4; ++mt)
#pragma unroll
        for (int nf = 0; nf < 2; ++nf) eacc[mt][nf] = (f32x4){0.f, 0.f, 0.f, 0.f};
#pragma unroll
    for (int ks = 0; ks < 2; ++ks) {
        bf16x8 a[4], b[2];
#pragma unroll
        for (int mt = 0; mt < 4; ++mt)
            a[mt] = *(const bf16x8*)&Vg[((size_t)h * 64 + mt * 16 + fr) * 64 + ks * 32 + quad * 8];
#pragma unroll
        for (int nf = 0; nf < 2; ++nf)
            b[nf] = *(const bf16x8*)&u_s[(wv * 32 + nf * 16 + fr) * 72 + ks * 32 + quad * 8];
#pragma unroll
        for (int mt = 0; mt < 4; ++mt)
#pragma unroll
            for (int nf = 0; nf < 2; ++nf)
                eacc[mt][nf] = __builtin_amdgcn_mfma_f32_16x16x32_bf16(a[mt], b[nf], eacc[mt][nf], 0, 0, 0);
    }
#pragma unroll
    for (int mt = 0; mt < 4; ++mt)               // E -> Eo_s [bc][comp], packed pairs
#pragma unroll
        for (int nf = 0; nf < 2; ++nf) {
            int bc = wv * 32 + nf * 16 + fr;
#pragma unroll
            for (int r = 0; r < 4; r += 2) {
                int comp = mt * 16 + quad * 4 + r;
                *(unsigned int*)&Eo_s[bc * 72 + comp] =
                    (unsigned int)f2bu(eacc[mt][nf][r]) | ((unsigned int)f2bu(eacc[mt][nf][r + 1]) << 16);
            }
        }
    __syncthreads();                             // Eo ready
    {                                            // in-block carry scan: thread = (b_local, n)
        int bl = tid >> 5, n = tid & 31;
        float2 a = PA[n * HDIM + h];
        float cr = 0.f, ci = 0.f;
#pragma unroll
        for (int c = 0; c < NCH; ++c) {
            int bc = bl * NCH + c;
            unsigned int ev = *(const unsigned int*)&Eo_s[bc * 72 + 2 * n];
            *(unsigned int*)&c_s[bc * 72 + 2 * n] =
                (unsigned int)f2bu(cr) | ((unsigned int)f2bu(ci) << 16);
            float er = bu2f((unsigned short)(ev & 0xffff));
            float ei = bu2f((unsigned short)(ev >> 16));
            float nr = fmaf(a.x, cr, fmaf(-a.y, ci, er));
            ci = fmaf(a.x, ci, fmaf(a.y, cr, ei));
            cr = nr;
        }
    }
    __syncthreads();                             // carries + T fill complete; Eo reusable
    bf16* o_s = Eo_s;
    f32x4 acc[4][2];
#pragma unroll
    for (int mt = 0; mt < 4; ++mt)
#pragma unroll
        for (int nf = 0; nf < 2; ++nf) acc[mt][nf] = (f32x4){0.f, 0.f, 0.f, 0.f};
#pragma unroll
    for (int ks = 0; ks < 4; ++ks) {
        bf16x8 a[4], b[2];
#pragma unroll
        for (int mt = 0; mt < 4; ++mt)
            a[mt] = *(const bf16x8*)&A_s[(mt * 16 + fr) * 136 + ks * 32 + quad * 8];
#pragma unroll
        for (int nf = 0; nf < 2; ++nf) {
            int row = (wv * 32 + nf * 16 + fr) * 72;
            b[nf] = (ks < 2) ? *(const bf16x8*)&u_s[row + ks * 32 + quad * 8]
                             : *(const bf16x8*)&c_s[row + (ks - 2) * 32 + quad * 8];
        }
#pragma unroll
        for (int mt = 0; mt < 4; ++mt)
#pragma unroll
            for (int nf = 0; nf < 2; ++nf)
                acc[mt][nf] = __builtin_amdgcn_mfma_f32_16x16x32_bf16(a[mt], b[nf], acc[mt][nf], 0, 0, 0);
    }
    float Dv = Dw[h];
#pragma unroll
    for (int mt = 0; mt < 4; ++mt)
#pragma unroll
        for (int nf = 0; nf < 2; ++nf) {
            int bcl = wv * 32 + nf * 16 + fr;
#pragma unroll
            for (int r = 0; r < 4; ++r) {
                int l = mt * 16 + quad * 4 + r;
                float u = __bfloat162float(u_s[bcl * 72 + l]);
                float v = fmaf(Dv, u, acc[mt][nf][r]);
                float z2 = 1.5957691216057308f * (v + 0.044715f * v * v * v);
                o_s[bcl * 72 + l] = __float2bfloat16(v / (1.f + __expf(-z2)));
            }
        }
    __syncthreads();
#pragma unroll
    for (int i = 0; i < 4; ++i) {                // coalesced Yt store
        int q = tid + i * 256, row = q >> 3, c8 = q & 7;
        *(uint4*)&Yt[(size_t)h * M_ROWS + (size_t)(bc0 + row) * 64 + c8 * 8] =
            *(uint4*)&o_s[row * 72 + c8 * 8];
    }
}

// ---------------- fused GLU + residual-LN (+ Ut emit, or decoder at last layer) ----------------
// grid M_ROWS/64, block 256; block owns 64 complete H rows; wave w covers n in [w*64,(w+1)*64)
__global__ __launch_bounds__(256) void k_gluln(const bf16* __restrict__ Yt,
                                               const bf16* __restrict__ Wt,
                                               const float* __restrict__ wb,
                                               float* __restrict__ Hb,
                                               const float* __restrict__ lnw,
                                               const float* __restrict__ lnb,
                                               bf16* __restrict__ Ut,
                                               const float* __restrict__ dw,
                                               const float* __restrict__ db,
                                               float* __restrict__ outp,
                                               int mode) {                  // 0: H+Ut, 1: decoder
    __shared__ bf16 A_s[64 * 72];                // [m][k-swizzled]
    __shared__ bf16 t_s[256 * 72];               // [n][m] normalized bf16
    __shared__ float red[2][4][64];
    __shared__ float stat[2][64];
    __shared__ float w_s[256], b_s[256];
    __shared__ float dw_s[HDIM * DOUT];
    __shared__ float db_s[16];
    int tid = threadIdx.x;
    int lane = tid & 63, wv = tid >> 6;
    int quad = lane >> 4, fr = lane & 15;
    int m0 = blockIdx.x * 64, n0 = wv * 64;
    int mg = tid & 31, hg = (tid >> 5) & 7;      // staging: 32 m-groups(2m) x 8 h-groups(8h)
    w_s[tid] = lnw[tid]; b_s[tid] = lnb[tid];
    if (mode == 1) {
        for (int e = tid; e < HDIM * DOUT; e += 256) dw_s[e] = dw[e];
        if (tid < DOUT) db_s[tid] = db[tid];
    }
    f32x4 acc1[4][4], acc2[4][4];
#pragma unroll
    for (int mt = 0; mt < 4; ++mt)
#pragma unroll
        for (int nt = 0; nt < 4; ++nt) {
            acc1[mt][nt] = (f32x4){0.f,0.f,0.f,0.f};
            acc2[mt][nt] = (f32x4){0.f,0.f,0.f,0.f};
        }
    for (int kt = 0; kt < HDIM; kt += 64) {
        {                                        // A tile: 64m x 64k from Yt[h][m], reg transpose
            unsigned int rowv[8];
#pragma unroll
            for (int e = 0; e < 8; ++e)
                rowv[e] = *(const unsigned int*)&Yt[(size_t)(kt + hg * 8 + e) * M_ROWS + m0 + mg * 2];
#pragma unroll
            for (int j = 0; j < 2; ++j) {
                unsigned int pk[4];
#pragma unroll
                for (int k2 = 0; k2 < 4; ++k2) {
                    unsigned int lo = (rowv[2 * k2]     >> (16 * j)) & 0xffffu;
                    unsigned int hi = (rowv[2 * k2 + 1] >> (16 * j)) & 0xffffu;
                    pk[k2] = lo | (hi << 16);
                }
                int m = mg * 2 + j;
                int phys = hg ^ ((m >> 3) & 7);
                *(uint4*)&A_s[m * 72 + phys * 8] = *(uint4*)pk;
            }
        }
        __syncthreads();
#pragma unroll
        for (int s = 0; s < 2; ++s) {
            bf16x8 a[4], b1[4], b2[4];
#pragma unroll
            for (int mt = 0; mt < 4; ++mt) {
                int ml = mt * 16 + fr;
                int phys = (s * 4 + quad) ^ ((ml >> 3) & 7);
                a[mt] = *(const bf16x8*)&A_s[ml * 72 + phys * 8];
            }
#pragma unroll
            for (int nt = 0; nt < 4; ++nt) {     // B straight from global (L2-hot)
                b1[nt] = *(const bf16x8*)&Wt[(size_t)(n0 + nt * 16 + fr) * HDIM + kt + s * 32 + quad * 8];
                b2[nt] = *(const bf16x8*)&Wt[(size_t)(256 + n0 + nt * 16 + fr) * HDIM + kt + s * 32 + quad * 8];
            }
#pragma unroll
            for (int mt = 0; mt < 4; ++mt)
#pragma unroll
                for (int nt = 0; nt < 4; ++nt) {
                    acc1[mt][nt] = __builtin_amdgcn_mfma_f32_16x16x32_bf16(a[mt], b1[nt], acc1[mt][nt], 0, 0, 0);
                    acc2[mt][nt] = __builtin_amdgcn_mfma_f32_16x16x32_bf16(a[mt], b2[nt], acc2[mt][nt], 0, 0, 0);
                }
        }
        __syncthreads();
    }
    // pass 1: GLU + residual into acc1; row partial sums
    float rs[16], rq[16];
#pragma unroll
    for (int i = 0; i < 16; ++i) { rs[i] = 0.f; rq[i] = 0.f; }
#pragma unroll
    for (int mt = 0; mt < 4; ++mt)
#pragma unroll
        for (int nt = 0; nt < 4; ++nt) {
            int n = n0 + nt * 16 + fr;
            float b1v = wb[n], b2v = wb[HDIM + n];
#pragma unroll
            for (int r = 0; r < 4; ++r) {
                int ml = mt * 16 + quad * 4 + r;
                float z1 = acc1[mt][nt][r] + b1v;
                float z2 = acc2[mt][nt][r] + b2v;
                float g = z1 / (1.0f + __expf(-z2));
                float rv = g + Hb[(size_t)(m0 + ml) * HDIM + n];
                acc1[mt][nt][r] = rv;
                rs[mt * 4 + r] += rv;
                rq[mt * 4 + r] += rv * rv;
            }
        }
#pragma unroll
    for (int i = 0; i < 16; ++i) {               // reduce over fr (16 lanes within quad)
        rs[i] += __shfl_xor(rs[i], 1, 64); rq[i] += __shfl_xor(rq[i], 1, 64);
        rs[i] += __shfl_xor(rs[i], 2, 64); rq[i] += __shfl_xor(rq[i], 2, 64);
        rs[i] += __shfl_xor(rs[i], 4, 64); rq[i] += __shfl_xor(rq[i], 4, 64);
        rs[i] += __shfl_xor(rs[i], 8, 64); rq[i] += __shfl_xor(rq[i], 8, 64);
    }
    if (fr == 0) {
#pragma unroll
        for (int i = 0; i < 16; ++i) {
            int ml = (i >> 2) * 16 + quad * 4 + (i & 3);
            red[0][wv][ml] = rs[i];
            red[1][wv][ml] = rq[i];
        }
    }
    __syncthreads();
    if (tid < 64) {
        float s  = red[0][0][tid] + red[0][1][tid] + red[0][2][tid] + red[0][3][tid];
        float s2 = red[1][0][tid] + red[1][1][tid] + red[1][2][tid] + red[1][3][tid];
        float mean = s * (1.f / HDIM);
        float var = s2 * (1.f / HDIM) - mean * mean;
        stat[0][tid] = mean;
        stat[1][tid] = rsqrtf(var + 1e-5f);
    }
    __syncthreads();
    // pass 2: normalize; write H (mode 0) + stage t_s[n][m]
#pragma unroll
    for (int mt = 0; mt < 4; ++mt)
#pragma unroll
        for (int nt = 0; nt < 4; ++nt) {
            int n = n0 + nt * 16 + fr;
#pragma unroll
            for (int r = 0; r < 4; ++r) {
                int ml = mt * 16 + quad * 4 + r;
                float val = (acc1[mt][nt][r] - stat[0][ml]) * stat[1][ml] * w_s[n] + b_s[n];
                if (mode == 0) Hb[(size_t)(m0 + ml) * HDIM + n] = val;
                t_s[n * 72 + ml] = __float2bfloat16(val);
            }
        }
    __syncthreads();
    if (mode == 0) {
#pragma unroll
        for (int i = 0; i < 8; ++i) {            // coalesced Ut store: 256 h rows x 64 m
            int q = tid + i * 256, hh = q >> 3, seg = q & 7;
            *(uint4*)&Ut[(size_t)hh * M_ROWS + m0 + seg * 8] = *(uint4*)&t_s[hh * 72 + seg * 8];
        }
    } else {                                     // decoder from t_s
        for (int q = tid; q < 64 * DOUT; q += 256) {
            int ml = q / DOUT, o = q - ml * DOUT;
            float acc = db_s[o];
#pragma unroll 8
            for (int hh = 0; hh < HDIM; ++hh)
                acc = fmaf(__bfloat162float(t_s[hh * 72 + ml]), dw_s[hh * DOUT + o], acc);
            outp[(size_t)(m0 + ml) * DOUT + o] = acc;
        }
    }
}

extern "C" void kernel_launch(void* const* d_in, const int* in_sizes, int n_in,
                              void* d_out, int out_size, void* d_ws, size_t ws_size,
                              hipStream_t stream) {
    const float* x        = (const float*)d_in[0];
    const float* enc_w    = (const float*)d_in[1];
    const float* enc_b    = (const float*)d_in[2];
    const float* log_dt   = (const float*)d_in[3];
    const float* A_re_log = (const float*)d_in[4];
    const float* A_im     = (const float*)d_in[5];
    const float* B_re     = (const float*)d_in[6];
    const float* B_im     = (const float*)d_in[7];
    const float* C_re     = (const float*)d_in[8];
    const float* C_im     = (const float*)d_in[9];
    const float* Dp       = (const float*)d_in[10];
    const float* ln_w     = (const float*)d_in[11];
    const float* ln_b     = (const float*)d_in[12];
    const float* out_w    = (const float*)d_in[13];
    const float* out_b    = (const float*)d_in[14];
    const float* dec_w    = (const float*)d_in[15];
    const float* dec_b    = (const float*)d_in[16];
    float* outp = (float*)d_out;

    float* w = (float*)d_ws;
    const size_t PWE = (size_t)NLAYERS * NSTATE * HDIM;   // 32768
    const size_t MH  = (size_t)M_ROWS * HDIM;             // 8388608
    const size_t VME = (size_t)NLAYERS * HDIM * 64 * 64;  // 4M elems/matrix
    float2* PA64 = (float2*)(w + 4 * PWE);                // 256 KB
    float*  Td   = w + 6 * PWE;                           // 270 KB
    float*  Hbuf = Td + (size_t)NLAYERS * HDIM * 66;      // 33.5 MB fp32
    bf16*   Ut   = (bf16*)(Hbuf + MH);                    // 16.7 MB
    bf16*   Yt   = Ut + MH;                               // 16.7 MB
    bf16*   Wt   = Yt + 2 * MH;                           // 1 MB (skip dead G slot)
    bf16*   Wet  = Wt + (size_t)NLAYERS * 512 * HDIM;     // 64 KB
    bf16*   Vg   = Wet + (size_t)HDIM * DIN;              // 8 MB (all layers)
    bf16*   Mg   = Vg + VME;                              // 8 MB (all layers)

    {
        int total = VMB_ + TDB_ + PAB_ + WCB_ + HDIM * DIN / 256;
        k_setup<<<total, 256, 0, stream>>>(log_dt, A_re_log, A_im, B_re, B_im, C_re, C_im,
                                           out_w, enc_w, Td, Vg, Mg, PA64, Wt, Wet);
    }

    dim3 ge(M_ROWS / 128, HDIM / 64);
    k_enc2<<<ge, 256, 0, stream>>>(x, Wet, enc_b, Hbuf, Ut);

    dim3 gconv(HDIM, NBC / 128);
    for (int layer = 0; layer < NLAYERS; ++layer) {
        const float2* pal = PA64 + (size_t)layer * NSTATE * HDIM;
        const float*  tdl = Td + (size_t)layer * HDIM * 66;
        const bf16*   vgl = Vg + (size_t)layer * HDIM * 64 * 64;
        const bf16*   mgl = Mg + (size_t)layer * HDIM * 64 * 64;
        k_conv<<<gconv, 256, 0, stream>>>(Ut, vgl, mgl, tdl, pal, Dp + layer * HDIM, Yt);
        k_gluln<<<M_ROWS / 64, 256, 0, stream>>>(Yt, Wt + (size_t)layer * 512 * HDIM,
                                                 out_b + layer * 2 * HDIM, Hbuf,
                                                 ln_w + layer * HDIM, ln_b + layer * HDIM,
                                                 Ut, dec_w, dec_b, outp,
                                                 layer == NLAYERS - 1 ? 1 : 0);
    }
}

// Round 18
// 392.782 us; speedup vs baseline: 1.0377x; 1.0377x over previous
//
#include <hip/hip_runtime.h>
#include <hip/hip_bf16.h>
#include <math.h>

#define B_SZ    32
#define LSEQ    1024
#define DIN     128
#define HDIM    256
#define NLAYERS 4
#define NSTATE  32
#define DOUT    10
#define M_ROWS  (B_SZ*LSEQ)   // 32768
#define CH      64            // scan chunk length
#define NCH     (LSEQ/CH)     // 16 chunks
#define NBC     (B_SZ*NCH)    // 512 chunk-columns

typedef __hip_bfloat16 bf16;
typedef __attribute__((ext_vector_type(8))) short bf16x8;
typedef __attribute__((ext_vector_type(4))) float f32x4;

__device__ __forceinline__ unsigned short f2bu(float x) {
    bf16 b = __float2bfloat16(x);
    return *(unsigned short*)&b;
}
__device__ __forceinline__ float bu2f(unsigned short u) {
    bf16 b = *(bf16*)&u;
    return __bfloat162float(b);
}

// inline S4D discretization: returns (dtAre, dtAim, Wre, Wim)
__device__ __forceinline__ float4 s4param(const float* __restrict__ log_dt,
                                          const float* __restrict__ A_re_log,
                                          const float* __restrict__ A_im,
                                          const float* __restrict__ B_re,
                                          const float* __restrict__ B_im,
                                          const float* __restrict__ C_re,
                                          const float* __restrict__ C_im,
                                          int layer, int h, int n) {
    int hn = layer * HDIM + h;
    int idx = hn * NSTATE + n;
    float dt   = expf(log_dt[hn]);
    float Are  = -expf(A_re_log[idx]);
    float Aim  = A_im[idx];
    float dtAre = dt * Are, dtAim = dt * Aim;
    float ea   = expf(dtAre);
    float dAre = ea * cosf(dtAim), dAim = ea * sinf(dtAim);
    float nre = dAre - 1.0f, nim = dAim;
    float inv = 1.0f / (Are * Are + Aim * Aim);
    float tre = (nre * Are + nim * Aim) * inv;
    float tim = (nim * Are - nre * Aim) * inv;
    float Brv = B_re[idx], Biv = B_im[idx];
    float dBre = Brv * tre - Biv * tim;
    float dBim = Brv * tim + Biv * tre;
    float Crv = C_re[idx], Civ = C_im[idx];
    float Wre = Crv * dBre - Civ * dBim;
    float Wim = Crv * dBim + Civ * dBre;
    return make_float4(dtAre, dtAim, Wre, Wim);
}

// ---------------- ONE setup kernel: V/M, Td, PA64, weight transposes ----------------
#define VMB_ (NLAYERS*HDIM*64*32/256)    // 32768
#define TDB_ ((NLAYERS*HDIM*66+255)/256) // 264
#define PAB_ (NLAYERS*NSTATE*HDIM/256)   // 128
#define WCB_ (NLAYERS*512*256/256)       // 2048
__global__ void k_setup(const float* __restrict__ log_dt, const float* __restrict__ A_re_log,
                        const float* __restrict__ A_im, const float* __restrict__ B_re,
                        const float* __restrict__ B_im, const float* __restrict__ C_re,
                        const float* __restrict__ C_im, const float* __restrict__ out_w,
                        const float* __restrict__ enc_w, float* __restrict__ Td,
                        bf16* __restrict__ Vg, bf16* __restrict__ Mg,
                        float2* __restrict__ PA64, bf16* __restrict__ Wt,
                        bf16* __restrict__ Wet) {
    const float inv2pi = 0.15915494309189535f;
    const float twopi  = 6.283185307179586f;
    int bx = blockIdx.x;
    if (bx < VMB_) {                                 // V/M pair-elements
        int gid = bx * 256 + threadIdx.x;
        int jp = (gid & 31) * 2;
        int row = gid >> 5;                          // ((layer*256+h)*64)+comp
        int comp = row & 63, h = (row >> 6) & 255, layer = row >> 14;
        int n = comp >> 1, isIm = comp & 1;
        float4 q = s4param(log_dt, A_re_log, A_im, B_re, B_im, C_re, C_im, layer, h, n);
        unsigned int vpk = 0, mpk = 0;
#pragma unroll
        for (int e = 0; e < 2; ++e) {
            int j = jp + e;
            float dv = (float)(63 - j);
            float magv = __expf(dv * q.x);
            float pr = dv * q.y * inv2pi;
            float th = (pr - floorf(pr)) * twopi;
            float c = __cosf(th), s = __sinf(th);
            float vre = magv * (q.z * c - q.w * s);
            float vim = magv * (q.z * s + q.w * c);
            vpk |= (unsigned int)f2bu(isIm ? vim : vre) << (16 * e);
            float dm = (float)(j + 1);
            float magm = __expf(dm * q.x);
            float pr2 = dm * q.y * inv2pi;
            float th2 = (pr2 - floorf(pr2)) * twopi;
            float mv = isIm ? (-2.f * magm * __sinf(th2)) : (2.f * magm * __cosf(th2));
            mpk |= (unsigned int)f2bu(mv) << (16 * e);
        }
        ((unsigned int*)Vg)[(size_t)row * 32 + (jp >> 1)] = vpk;
        ((unsigned int*)Mg)[(size_t)row * 32 + (jp >> 1)] = mpk;
    } else if (bx < VMB_ + TDB_) {                   // Td
        int gid = (bx - VMB_) * 256 + threadIdx.x;
        int d = gid % 66;
        int lh = gid / 66;
        if (lh < NLAYERS * HDIM && d < 65) {
            int layer = lh >> 8, h = lh & 255;
            float fd = (float)d;
            float acc = 0.f;
            for (int n = 0; n < NSTATE; ++n) {
                float4 q = s4param(log_dt, A_re_log, A_im, B_re, B_im, C_re, C_im, layer, h, n);
                float mag = __expf(fd * q.x);
                float pr = fd * q.y * inv2pi;
                float th = (pr - floorf(pr)) * twopi;
                acc += mag * (q.z * __cosf(th) - q.w * __sinf(th));
            }
            Td[(size_t)lh * 66 + d] = 2.f * acc;
        }
    } else if (bx < VMB_ + TDB_ + PAB_) {            // PA64 = dA^64 per (layer,n,h)
        int idx = (bx - VMB_ - TDB_) * 256 + threadIdx.x;
        int h = idx & 255, n = (idx >> 8) & 31, layer = idx >> 13;
        float4 q = s4param(log_dt, A_re_log, A_im, B_re, B_im, C_re, C_im, layer, h, n);
        float e64 = expf(64.0f * q.x);
        float ph  = 64.0f * q.y;
        PA64[idx] = make_float2(e64 * cosf(ph), e64 * sinf(ph));
    } else if (bx < VMB_ + TDB_ + PAB_ + WCB_) {     // Wt transpose
        int idx = (bx - VMB_ - TDB_ - PAB_) * 256 + threadIdx.x;
        int k = idx & 255;
        int n = (idx >> 8) & 511;
        int layer = idx >> 17;
        Wt[idx] = __float2bfloat16(out_w[((size_t)(layer * 256 + k)) * 512 + n]);
    } else {                                         // Wet transpose
        int idx = (bx - VMB_ - TDB_ - PAB_ - WCB_) * 256 + threadIdx.x;
        int k = idx & 127, n = idx >> 7;
        Wet[idx] = __float2bfloat16(enc_w[(size_t)k * HDIM + n]);
    }
}

// ---------------- encoder GEMM (bf16 MFMA): H = X@We + b, + transposed Ut output ----------------
__global__ __launch_bounds__(256) void k_enc2(const float* __restrict__ X, const bf16* __restrict__ Wet,
                                              const float* __restrict__ bias, float* __restrict__ H,
                                              bf16* __restrict__ Ut) {
    __shared__ bf16 A_s[128 * 136];
    __shared__ bf16 B_s[64 * 136];
    int tid = threadIdx.x;
    int lane = tid & 63, wv = tid >> 6, quad = lane >> 4, fr = lane & 15;
    int m0 = blockIdx.x * 128, n0 = blockIdx.y * 64;
#pragma unroll
    for (int i = 0; i < 16; ++i) {               // stage X fp32 -> bf16 [m][k]
        int q = tid + i * 256, row = q >> 5, seg = q & 31;
        float4 v = *(const float4*)&X[(size_t)(m0 + row) * DIN + seg * 4];
        bf16* dst = &A_s[row * 136 + seg * 4];
        dst[0] = __float2bfloat16(v.x); dst[1] = __float2bfloat16(v.y);
        dst[2] = __float2bfloat16(v.z); dst[3] = __float2bfloat16(v.w);
    }
#pragma unroll
    for (int i = 0; i < 4; ++i) {                // stage Wet [n][k]
        int q = tid + i * 256, row = q >> 4, seg = q & 15;
        *(uint4*)&B_s[row * 136 + seg * 8] = *(const uint4*)&Wet[(size_t)(n0 + row) * DIN + seg * 8];
    }
    __syncthreads();
    f32x4 acc[2][4];
#pragma unroll
    for (int mt = 0; mt < 2; ++mt)
#pragma unroll
        for (int nt = 0; nt < 4; ++nt) acc[mt][nt] = (f32x4){0.f, 0.f, 0.f, 0.f};
#pragma unroll
    for (int ks = 0; ks < 4; ++ks) {
        bf16x8 a[2], b[4];
#pragma unroll
        for (int mt = 0; mt < 2; ++mt)
            a[mt] = *(const bf16x8*)&A_s[(wv * 32 + mt * 16 + fr) * 136 + ks * 32 + quad * 8];
#pragma unroll
        for (int nt = 0; nt < 4; ++nt)
            b[nt] = *(const bf16x8*)&B_s[(nt * 16 + fr) * 136 + ks * 32 + quad * 8];
#pragma unroll
        for (int mt = 0; mt < 2; ++mt)
#pragma unroll
            for (int nt = 0; nt < 4; ++nt)
                acc[mt][nt] = __builtin_amdgcn_mfma_f32_16x16x32_bf16(a[mt], b[nt], acc[mt][nt], 0, 0, 0);
    }
    __syncthreads();                             // B_s reuse as transpose bounce
#pragma unroll
    for (int mt = 0; mt < 2; ++mt)
#pragma unroll
        for (int nt = 0; nt < 4; ++nt) {
            int n = n0 + nt * 16 + fr;
            float bv = bias[n];
#pragma unroll
            for (int r = 0; r < 4; ++r) {
                int m = m0 + wv * 32 + mt * 16 + quad * 4 + r;
                float hv = acc[mt][nt][r] + bv;
                H[(size_t)m * HDIM + n] = hv;
                B_s[(nt * 16 + fr) * 136 + (wv * 32 + mt * 16 + quad * 4 + r)] = __float2bfloat16(hv);
            }
        }
    __syncthreads();
#pragma unroll
    for (int i = 0; i < 4; ++i) {                // coalesced Ut store [h][m]
        int q = tid + i * 256, row = q >> 4, seg = q & 15;
        *(uint4*)&Ut[(size_t)(n0 + row) * M_ROWS + m0 + seg * 8] = *(uint4*)&B_s[row * 136 + seg * 8];
    }
}

// ---------------- fused conv: E-MFMA + in-LDS carry scan + T|M-MFMA + GELU ----------------
__global__ __launch_bounds__(256) void k_conv(const bf16* __restrict__ Ut,
                                              const bf16* __restrict__ Vg,
                                              const bf16* __restrict__ Mg,
                                              const float* __restrict__ Tdl,
                                              const float2* __restrict__ PA,
                                              const float* __restrict__ Dw,
                                              bf16* __restrict__ Yt) {
    __shared__ bf16 u_s[128 * 72];               // [bc][j]
    __shared__ bf16 A_s[64 * 136];               // [l][k2], k2<64: T, k2>=64: M
    __shared__ bf16 Eo_s[128 * 72];              // [bc][comp] E bounce; reused as o_s
    __shared__ bf16 c_s[128 * 72];               // [bc][comp] carries
    __shared__ float Td_s[65];
    int h = blockIdx.x, bc0 = blockIdx.y * 128;
    int tid = threadIdx.x;
    int lane = tid & 63, wv = tid >> 6, quad = lane >> 4, fr = lane & 15;
    if (tid < 65) Td_s[tid] = Tdl[(size_t)h * 66 + tid];
#pragma unroll
    for (int i = 0; i < 2; ++i) {                // stage M transposed into A_s cols 64..127
        int q = tid + i * 256, comp = q >> 3, seg = q & 7;
        uint4 v = *(const uint4*)&Mg[((size_t)h * 64 + comp) * 64 + seg * 8];
        const bf16* pv = (const bf16*)&v;
#pragma unroll
        for (int e = 0; e < 8; ++e) A_s[(seg * 8 + e) * 136 + 64 + comp] = pv[e];
    }
#pragma unroll
    for (int i = 0; i < 4; ++i) {                // stage u tile
        int q = tid + i * 256, row = q >> 3, c8 = q & 7;
        *(uint4*)&u_s[row * 72 + c8 * 8] =
            *(const uint4*)&Ut[(size_t)h * M_ROWS + (size_t)(bc0 + row) * 64 + c8 * 8];
    }
    __syncthreads();                             // u_s + Td_s ready
#pragma unroll
    for (int i = 0; i < 16; ++i) {               // Toeplitz T fill
        int q = tid + i * 256, l = q >> 6, j = q & 63, d = l - j;
        A_s[l * 136 + j] = __float2bfloat16(d >= 0 ? Td_s[d] : 0.f);
    }
    f32x4 eacc[4][2];
#pragma unroll
    for (int mt = 0; mt < 4; ++mt)
#pragma unroll
        for (int nf = 0; nf < 2; ++nf) eacc[mt][nf] = (f32x4){0.f, 0.f, 0.f, 0.f};
#pragma unroll
    for (int ks = 0; ks < 2; ++ks) {
        bf16x8 a[4], b[2];
#pragma unroll
        for (int mt = 0; mt < 4; ++mt)
            a[mt] = *(const bf16x8*)&Vg[((size_t)h * 64 + mt * 16 + fr) * 64 + ks * 32 + quad * 8];
#pragma unroll
        for (int nf = 0; nf < 2; ++nf)
            b[nf] = *(const bf16x8*)&u_s[(wv * 32 + nf * 16 + fr) * 72 + ks * 32 + quad * 8];
#pragma unroll
        for (int mt = 0; mt < 4; ++mt)
#pragma unroll
            for (int nf = 0; nf < 2; ++nf)
                eacc[mt][nf] = __builtin_amdgcn_mfma_f32_16x16x32_bf16(a[mt], b[nf], eacc[mt][nf], 0, 0, 0);
    }
#pragma unroll
    for (int mt = 0; mt < 4; ++mt)               // E -> Eo_s [bc][comp], packed pairs
#pragma unroll
        for (int nf = 0; nf < 2; ++nf) {
            int bc = wv * 32 + nf * 16 + fr;
#pragma unroll
            for (int r = 0; r < 4; r += 2) {
                int comp = mt * 16 + quad * 4 + r;
                *(unsigned int*)&Eo_s[bc * 72 + comp] =
                    (unsigned int)f2bu(eacc[mt][nf][r]) | ((unsigned int)f2bu(eacc[mt][nf][r + 1]) << 16);
            }
        }
    __syncthreads();                             // Eo ready
    {                                            // in-block carry scan: thread = (b_local, n)
        int bl = tid >> 5, n = tid & 31;
        float2 a = PA[n * HDIM + h];
        float cr = 0.f, ci = 0.f;
#pragma unroll
        for (int c = 0; c < NCH; ++c) {
            int bc = bl * NCH + c;
            unsigned int ev = *(const unsigned int*)&Eo_s[bc * 72 + 2 * n];
            *(unsigned int*)&c_s[bc * 72 + 2 * n] =
                (unsigned int)f2bu(cr) | ((unsigned int)f2bu(ci) << 16);
            float er = bu2f((unsigned short)(ev & 0xffff));
            float ei = bu2f((unsigned short)(ev >> 16));
            float nr = fmaf(a.x, cr, fmaf(-a.y, ci, er));
            ci = fmaf(a.x, ci, fmaf(a.y, cr, ei));
            cr = nr;
        }
    }
    __syncthreads();                             // carries + T fill complete; Eo reusable
    bf16* o_s = Eo_s;
    f32x4 acc[4][2];
#pragma unroll
    for (int mt = 0; mt < 4; ++mt)
#pragma unroll
        for (int nf = 0; nf < 2; ++nf) acc[mt][nf] = (f32x4){0.f, 0.f, 0.f, 0.f};
#pragma unroll
    for (int ks = 0; ks < 4; ++ks) {
        bf16x8 a[4], b[2];
#pragma unroll
        for (int mt = 0; mt < 4; ++mt)
            a[mt] = *(const bf16x8*)&A_s[(mt * 16 + fr) * 136 + ks * 32 + quad * 8];
#pragma unroll
        for (int nf = 0; nf < 2; ++nf) {
            int row = (wv * 32 + nf * 16 + fr) * 72;
            b[nf] = (ks < 2) ? *(const bf16x8*)&u_s[row + ks * 32 + quad * 8]
                             : *(const bf16x8*)&c_s[row + (ks - 2) * 32 + quad * 8];
        }
#pragma unroll
        for (int mt = 0; mt < 4; ++mt)
#pragma unroll
            for (int nf = 0; nf < 2; ++nf)
                acc[mt][nf] = __builtin_amdgcn_mfma_f32_16x16x32_bf16(a[mt], b[nf], acc[mt][nf], 0, 0, 0);
    }
    float Dv = Dw[h];
#pragma unroll
    for (int mt = 0; mt < 4; ++mt)
#pragma unroll
        for (int nf = 0; nf < 2; ++nf) {
            int bcl = wv * 32 + nf * 16 + fr;
#pragma unroll
            for (int r = 0; r < 4; ++r) {
                int l = mt * 16 + quad * 4 + r;
                float u = __bfloat162float(u_s[bcl * 72 + l]);
                float v = fmaf(Dv, u, acc[mt][nf][r]);
                float z2 = 1.5957691216057308f * (v + 0.044715f * v * v * v);
                o_s[bcl * 72 + l] = __float2bfloat16(v / (1.f + __expf(-z2)));
            }
        }
    __syncthreads();
#pragma unroll
    for (int i = 0; i < 4; ++i) {                // coalesced Yt store
        int q = tid + i * 256, row = q >> 3, c8 = q & 7;
        *(uint4*)&Yt[(size_t)h * M_ROWS + (size_t)(bc0 + row) * 64 + c8 * 8] =
            *(uint4*)&o_s[row * 72 + c8 * 8];
    }
}

// ---------------- output GEMM + GLU, reads Yt [h][m] directly ----------------
// A-transpose via register 4mx8h micro-tiles + XOR-swizzled A_s (conflict-free, r15-proven)
__global__ __launch_bounds__(256) void k_glu2(const bf16* __restrict__ Yt,
                                              const bf16* __restrict__ Wt,
                                              const float* __restrict__ wb,
                                              bf16* __restrict__ G) {
    __shared__ bf16 A_s[128 * 72];               // [m][k-swizzled]
    __shared__ bf16 B1_s[64 * 72];
    __shared__ bf16 B2_s[64 * 72];
    int tid = threadIdx.x;
    int lane = tid & 63, wv = tid >> 6;
    int quad = lane >> 4, fr = lane & 15;
    int m0 = blockIdx.x * 128, n0 = blockIdx.y * 64;
    int mg = tid & 31, hg = tid >> 5;            // micro-tile coords: 32 m-groups x 8 h-groups
    f32x4 acc1[2][4], acc2[2][4];
#pragma unroll
    for (int mt = 0; mt < 2; ++mt)
#pragma unroll
        for (int nt = 0; nt < 4; ++nt) {
            acc1[mt][nt] = (f32x4){0.f,0.f,0.f,0.f};
            acc2[mt][nt] = (f32x4){0.f,0.f,0.f,0.f};
        }
    for (int kt = 0; kt < HDIM; kt += 64) {
        {                                        // A tile: 8 coalesced uint2 reads -> reg transpose
            uint2 rowv[8];
#pragma unroll
            for (int e = 0; e < 8; ++e)
                rowv[e] = *(const uint2*)&Yt[(size_t)(kt + hg * 8 + e) * M_ROWS + m0 + mg * 4];
#pragma unroll
            for (int j = 0; j < 4; ++j) {        // 4 swizzled uint4 writes
                unsigned int pk[4];
#pragma unroll
                for (int k2 = 0; k2 < 4; ++k2) {
                    unsigned int lo = ((const unsigned short*)&rowv[2 * k2])[j];
                    unsigned int hi = ((const unsigned short*)&rowv[2 * k2 + 1])[j];
                    pk[k2] = lo | (hi << 16);
                }
                int m = mg * 4 + j;
                int phys = hg ^ ((m >> 3) & 7);
                *(uint4*)&A_s[m * 72 + phys * 8] = *(uint4*)pk;
            }
        }
#pragma unroll
        for (int i = 0; i < 2; ++i) {
            int e = tid + i * 256, row = e >> 3, cm = e & 7;
            *(uint4*)&B1_s[row * 72 + cm * 8] =
                *(const uint4*)(Wt + (size_t)(n0 + row) * HDIM + kt + cm * 8);
            *(uint4*)&B2_s[row * 72 + cm * 8] =
                *(const uint4*)(Wt + (size_t)(256 + n0 + row) * HDIM + kt + cm * 8);
        }
        __syncthreads();
#pragma unroll
        for (int s = 0; s < 2; ++s) {
            bf16x8 a[2], b1[4], b2[4];
#pragma unroll
            for (int mt = 0; mt < 2; ++mt) {
                int ml = wv * 32 + mt * 16 + fr;
                int phys = (s * 4 + quad) ^ ((ml >> 3) & 7);
                a[mt] = *(const bf16x8*)&A_s[ml * 72 + phys * 8];
            }
#pragma unroll
            for (int nt = 0; nt < 4; ++nt) {
                b1[nt] = *(const bf16x8*)&B1_s[(nt * 16 + fr) * 72 + s * 32 + quad * 8];
                b2[nt] = *(const bf16x8*)&B2_s[(nt * 16 + fr) * 72 + s * 32 + quad * 8];
            }
#pragma unroll
            for (int mt = 0; mt < 2; ++mt)
#pragma unroll
                for (int nt = 0; nt < 4; ++nt) {
                    acc1[mt][nt] = __builtin_amdgcn_mfma_f32_16x16x32_bf16(a[mt], b1[nt], acc1[mt][nt], 0, 0, 0);
                    acc2[mt][nt] = __builtin_amdgcn_mfma_f32_16x16x32_bf16(a[mt], b2[nt], acc2[mt][nt], 0, 0, 0);
                }
        }
        __syncthreads();
    }
#pragma unroll
    for (int mt = 0; mt < 2; ++mt)
#pragma unroll
        for (int nt = 0; nt < 4; ++nt) {
            int n = n0 + nt * 16 + fr;
            float b1v = wb[n], b2v = wb[HDIM + n];
#pragma unroll
            for (int r = 0; r < 4; ++r) {
                int m = m0 + wv * 32 + mt * 16 + quad * 4 + r;
                float z1 = acc1[mt][nt][r] + b1v;
                float z2 = acc2[mt][nt][r] + b2v;
                G[(size_t)m * HDIM + n] = __float2bfloat16(z1 / (1.0f + __expf(-z2)));
            }
        }
}

// ---------------- residual + LayerNorm, 64-row tiles; mode 0: H+Ut, mode 1: decoder ----------------
__global__ __launch_bounds__(256) void k_ln2(const bf16* __restrict__ G, float* __restrict__ Hb,
                                             const float* __restrict__ w, const float* __restrict__ bb,
                                             bf16* __restrict__ Ut,
                                             const float* __restrict__ dw,
                                             const float* __restrict__ db,
                                             float* __restrict__ outp, int mode) {
    __shared__ bf16 t_s[256][72];
    __shared__ float red[2][4][64];
    __shared__ float stat[2][64];
    __shared__ float w_s[256], b_s[256];
    __shared__ float dw_s[HDIM * DOUT];
    __shared__ float db_s[16];
    int m0 = blockIdx.x * 64;
    int tid = threadIdx.x;
    int r = tid & 63, qd = tid >> 6;
    w_s[tid] = w[tid]; b_s[tid] = bb[tid];
    if (mode == 1) {
        for (int e = tid; e < HDIM * DOUT; e += 256) dw_s[e] = dw[e];
        if (tid < DOUT) db_s[tid] = db[tid];
    }
    const bf16* Gp = G + (size_t)(m0 + r) * HDIM + qd * 64;
    float*      Hp = Hb + (size_t)(m0 + r) * HDIM + qd * 64;
    float rv[64];
    float sum = 0.f, sq = 0.f;
#pragma unroll
    for (int j = 0; j < 64; j += 8) {
        uint4 gv = *(const uint4*)&Gp[j];
        const bf16* gp = (const bf16*)&gv;
        float4 h0 = *(const float4*)&Hp[j];
        float4 h1 = *(const float4*)&Hp[j + 4];
        float hv[8] = {h0.x, h0.y, h0.z, h0.w, h1.x, h1.y, h1.z, h1.w};
#pragma unroll
        for (int e = 0; e < 8; ++e) {
            float v = __bfloat162float(gp[e]) + hv[e];
            rv[j + e] = v; sum += v; sq += v * v;
        }
    }
    red[0][qd][r] = sum; red[1][qd][r] = sq;
    __syncthreads();
    if (tid < 64) {
        float s  = red[0][0][tid] + red[0][1][tid] + red[0][2][tid] + red[0][3][tid];
        float s2 = red[1][0][tid] + red[1][1][tid] + red[1][2][tid] + red[1][3][tid];
        float mean = s * (1.f / HDIM);
        float var = s2 * (1.f / HDIM) - mean * mean;
        stat[0][tid] = mean; stat[1][tid] = rsqrtf(var + 1e-5f);
    }
    __syncthreads();
    float mean = stat[0][r], rstd = stat[1][r];
#pragma unroll
    for (int j = 0; j < 64; ++j)
        rv[j] = (rv[j] - mean) * rstd * w_s[qd * 64 + j] + b_s[qd * 64 + j];
    if (mode == 0) {
#pragma unroll
        for (int j = 0; j < 64; j += 4)
            *(float4*)&Hp[j] = make_float4(rv[j], rv[j + 1], rv[j + 2], rv[j + 3]);
    }
#pragma unroll
    for (int j = 0; j < 64; ++j) t_s[qd * 64 + j][r] = __float2bfloat16(rv[j]);
    __syncthreads();
    if (mode == 0) {
#pragma unroll
        for (int i = 0; i < 8; ++i) {            // coalesced Ut store: 256 h rows x 64 m
            int q = tid + i * 256, hh = q >> 3, seg = q & 7;
            *(uint4*)&Ut[(size_t)hh * M_ROWS + m0 + seg * 8] = *(uint4*)&t_s[hh][seg * 8];
        }
    } else {                                     // decoder from t_s
        for (int q = tid; q < 64 * DOUT; q += 256) {
            int ml = q / DOUT, o = q - ml * DOUT;
            float acc = db_s[o];
#pragma unroll 8
            for (int hh = 0; hh < HDIM; ++hh)
                acc = fmaf(__bfloat162float(t_s[hh][ml]), dw_s[hh * DOUT + o], acc);
            outp[(size_t)(m0 + ml) * DOUT + o] = acc;
        }
    }
}

extern "C" void kernel_launch(void* const* d_in, const int* in_sizes, int n_in,
                              void* d_out, int out_size, void* d_ws, size_t ws_size,
                              hipStream_t stream) {
    const float* x        = (const float*)d_in[0];
    const float* enc_w    = (const float*)d_in[1];
    const float* enc_b    = (const float*)d_in[2];
    const float* log_dt   = (const float*)d_in[3];
    const float* A_re_log = (const float*)d_in[4];
    const float* A_im     = (const float*)d_in[5];
    const float* B_re     = (const float*)d_in[6];
    const float* B_im     = (const float*)d_in[7];
    const float* C_re     = (const float*)d_in[8];
    const float* C_im     = (const float*)d_in[9];
    const float* Dp       = (const float*)d_in[10];
    const float* ln_w     = (const float*)d_in[11];
    const float* ln_b     = (const float*)d_in[12];
    const float* out_w    = (const float*)d_in[13];
    const float* out_b    = (const float*)d_in[14];
    const float* dec_w    = (const float*)d_in[15];
    const float* dec_b    = (const float*)d_in[16];
    float* outp = (float*)d_out;

    float* w = (float*)d_ws;
    const size_t PWE = (size_t)NLAYERS * NSTATE * HDIM;   // 32768
    const size_t MH  = (size_t)M_ROWS * HDIM;             // 8388608
    const size_t VME = (size_t)NLAYERS * HDIM * 64 * 64;  // 4M elems/matrix
    float2* PA64 = (float2*)(w + 4 * PWE);                // 256 KB
    float*  Td   = w + 6 * PWE;                           // 270 KB
    float*  Hbuf = Td + (size_t)NLAYERS * HDIM * 66;      // 33.5 MB fp32
    bf16*   Ut   = (bf16*)(Hbuf + MH);                    // 16.7 MB
    bf16*   Yt   = Ut + MH;                               // 16.7 MB
    bf16*   G    = Yt + MH;                               // 16.7 MB
    bf16*   Wt   = G + MH;                                // 1 MB
    bf16*   Wet  = Wt + (size_t)NLAYERS * 512 * HDIM;     // 64 KB
    bf16*   Vg   = Wet + (size_t)HDIM * DIN;              // 8 MB (all layers)
    bf16*   Mg   = Vg + VME;                              // 8 MB (all layers)

    {
        int total = VMB_ + TDB_ + PAB_ + WCB_ + HDIM * DIN / 256;
        k_setup<<<total, 256, 0, stream>>>(log_dt, A_re_log, A_im, B_re, B_im, C_re, C_im,
                                           out_w, enc_w, Td, Vg, Mg, PA64, Wt, Wet);
    }

    dim3 ge(M_ROWS / 128, HDIM / 64);
    k_enc2<<<ge, 256, 0, stream>>>(x, Wet, enc_b, Hbuf, Ut);

    dim3 gconv(HDIM, NBC / 128);
    dim3 gg(M_ROWS / 128, HDIM / 64);
    for (int layer = 0; layer < NLAYERS; ++layer) {
        const float2* pal = PA64 + (size_t)layer * NSTATE * HDIM;
        const float*  tdl = Td + (size_t)layer * HDIM * 66;
        const bf16*   vgl = Vg + (size_t)layer * HDIM * 64 * 64;
        const bf16*   mgl = Mg + (size_t)layer * HDIM * 64 * 64;
        k_conv<<<gconv, 256, 0, stream>>>(Ut, vgl, mgl, tdl, pal, Dp + layer * HDIM, Yt);
        k_glu2<<<gg, 256, 0, stream>>>(Yt, Wt + (size_t)layer * 512 * HDIM,
                                       out_b + layer * 2 * HDIM, G);
        k_ln2<<<M_ROWS / 64, 256, 0, stream>>>(G, Hbuf, ln_w + layer * HDIM,
                                               ln_b + layer * HDIM, Ut, dec_w, dec_b, outp,
                                               layer == NLAYERS - 1 ? 1 : 0);
    }
}

// Round 19
// 373.835 us; speedup vs baseline: 1.0903x; 1.0507x over previous
//
#include <hip/hip_runtime.h>
#include <hip/hip_bf16.h>
#include <math.h>

#define B_SZ    32
#define LSEQ    1024
#define DIN     128
#define HDIM    256
#define NLAYERS 4
#define NSTATE  32
#define DOUT    10
#define M_ROWS  (B_SZ*LSEQ)   // 32768
#define CH      64            // scan chunk length
#define NCH     (LSEQ/CH)     // 16 chunks
#define NBC     (B_SZ*NCH)    // 512 chunk-columns

typedef __hip_bfloat16 bf16;
typedef __attribute__((ext_vector_type(8))) short bf16x8;
typedef __attribute__((ext_vector_type(4))) float f32x4;

__device__ __forceinline__ unsigned short f2bu(float x) {
    bf16 b = __float2bfloat16(x);
    return *(unsigned short*)&b;
}
__device__ __forceinline__ float bu2f(unsigned short u) {
    bf16 b = *(bf16*)&u;
    return __bfloat162float(b);
}

// inline S4D discretization: returns (dtAre, dtAim, Wre, Wim)
__device__ __forceinline__ float4 s4param(const float* __restrict__ log_dt,
                                          const float* __restrict__ A_re_log,
                                          const float* __restrict__ A_im,
                                          const float* __restrict__ B_re,
                                          const float* __restrict__ B_im,
                                          const float* __restrict__ C_re,
                                          const float* __restrict__ C_im,
                                          int layer, int h, int n) {
    int hn = layer * HDIM + h;
    int idx = hn * NSTATE + n;
    float dt   = expf(log_dt[hn]);
    float Are  = -expf(A_re_log[idx]);
    float Aim  = A_im[idx];
    float dtAre = dt * Are, dtAim = dt * Aim;
    float ea   = expf(dtAre);
    float dAre = ea * cosf(dtAim), dAim = ea * sinf(dtAim);
    float nre = dAre - 1.0f, nim = dAim;
    float inv = 1.0f / (Are * Are + Aim * Aim);
    float tre = (nre * Are + nim * Aim) * inv;
    float tim = (nim * Are - nre * Aim) * inv;
    float Brv = B_re[idx], Biv = B_im[idx];
    float dBre = Brv * tre - Biv * tim;
    float dBim = Brv * tim + Biv * tre;
    float Crv = C_re[idx], Civ = C_im[idx];
    float Wre = Crv * dBre - Civ * dBim;
    float Wim = Crv * dBim + Civ * dBre;
    return make_float4(dtAre, dtAim, Wre, Wim);
}

// ---------------- ONE setup kernel: V/M, Td, PA64, weight transposes ----------------
#define VMB_ (NLAYERS*HDIM*64*32/256)    // 32768
#define TDB_ ((NLAYERS*HDIM*66+255)/256) // 264
#define PAB_ (NLAYERS*NSTATE*HDIM/256)   // 128
#define WCB_ (NLAYERS*512*256/256)       // 2048
__global__ void k_setup(const float* __restrict__ log_dt, const float* __restrict__ A_re_log,
                        const float* __restrict__ A_im, const float* __restrict__ B_re,
                        const float* __restrict__ B_im, const float* __restrict__ C_re,
                        const float* __restrict__ C_im, const float* __restrict__ out_w,
                        const float* __restrict__ enc_w, float* __restrict__ Td,
                        bf16* __restrict__ Vg, bf16* __restrict__ Mg,
                        float2* __restrict__ PA64, bf16* __restrict__ Wt,
                        bf16* __restrict__ Wet) {
    const float inv2pi = 0.15915494309189535f;
    const float twopi  = 6.283185307179586f;
    int bx = blockIdx.x;
    if (bx < VMB_) {                                 // V/M pair-elements
        int gid = bx * 256 + threadIdx.x;
        int jp = (gid & 31) * 2;
        int row = gid >> 5;                          // ((layer*256+h)*64)+comp
        int comp = row & 63, h = (row >> 6) & 255, layer = row >> 14;
        int n = comp >> 1, isIm = comp & 1;
        float4 q = s4param(log_dt, A_re_log, A_im, B_re, B_im, C_re, C_im, layer, h, n);
        unsigned int vpk = 0, mpk = 0;
#pragma unroll
        for (int e = 0; e < 2; ++e) {
            int j = jp + e;
            float dv = (float)(63 - j);
            float magv = __expf(dv * q.x);
            float pr = dv * q.y * inv2pi;
            float th = (pr - floorf(pr)) * twopi;
            float c = __cosf(th), s = __sinf(th);
            float vre = magv * (q.z * c - q.w * s);
            float vim = magv * (q.z * s + q.w * c);
            vpk |= (unsigned int)f2bu(isIm ? vim : vre) << (16 * e);
            float dm = (float)(j + 1);
            float magm = __expf(dm * q.x);
            float pr2 = dm * q.y * inv2pi;
            float th2 = (pr2 - floorf(pr2)) * twopi;
            float mv = isIm ? (-2.f * magm * __sinf(th2)) : (2.f * magm * __cosf(th2));
            mpk |= (unsigned int)f2bu(mv) << (16 * e);
        }
        ((unsigned int*)Vg)[(size_t)row * 32 + (jp >> 1)] = vpk;
        ((unsigned int*)Mg)[(size_t)row * 32 + (jp >> 1)] = mpk;
    } else if (bx < VMB_ + TDB_) {                   // Td
        int gid = (bx - VMB_) * 256 + threadIdx.x;
        int d = gid % 66;
        int lh = gid / 66;
        if (lh < NLAYERS * HDIM && d < 65) {
            int layer = lh >> 8, h = lh & 255;
            float fd = (float)d;
            float acc = 0.f;
            for (int n = 0; n < NSTATE; ++n) {
                float4 q = s4param(log_dt, A_re_log, A_im, B_re, B_im, C_re, C_im, layer, h, n);
                float mag = __expf(fd * q.x);
                float pr = fd * q.y * inv2pi;
                float th = (pr - floorf(pr)) * twopi;
                acc += mag * (q.z * __cosf(th) - q.w * __sinf(th));
            }
            Td[(size_t)lh * 66 + d] = 2.f * acc;
        }
    } else if (bx < VMB_ + TDB_ + PAB_) {            // PA64 = dA^64 per (layer,n,h)
        int idx = (bx - VMB_ - TDB_) * 256 + threadIdx.x;
        int h = idx & 255, n = (idx >> 8) & 31, layer = idx >> 13;
        float4 q = s4param(log_dt, A_re_log, A_im, B_re, B_im, C_re, C_im, layer, h, n);
        float e64 = expf(64.0f * q.x);
        float ph  = 64.0f * q.y;
        PA64[idx] = make_float2(e64 * cosf(ph), e64 * sinf(ph));
    } else if (bx < VMB_ + TDB_ + PAB_ + WCB_) {     // Wt transpose
        int idx = (bx - VMB_ - TDB_ - PAB_) * 256 + threadIdx.x;
        int k = idx & 255;
        int n = (idx >> 8) & 511;
        int layer = idx >> 17;
        Wt[idx] = __float2bfloat16(out_w[((size_t)(layer * 256 + k)) * 512 + n]);
    } else {                                         // Wet transpose
        int idx = (bx - VMB_ - TDB_ - PAB_ - WCB_) * 256 + threadIdx.x;
        int k = idx & 127, n = idx >> 7;
        Wet[idx] = __float2bfloat16(enc_w[(size_t)k * HDIM + n]);
    }
}

// ---------------- encoder GEMM (bf16 MFMA): H(bf16) = X@We + b, + transposed Ut ----------------
__global__ __launch_bounds__(256) void k_enc2(const float* __restrict__ X, const bf16* __restrict__ Wet,
                                              const float* __restrict__ bias, bf16* __restrict__ H,
                                              bf16* __restrict__ Ut) {
    __shared__ bf16 A_s[128 * 136];
    __shared__ bf16 B_s[64 * 136];
    int tid = threadIdx.x;
    int lane = tid & 63, wv = tid >> 6, quad = lane >> 4, fr = lane & 15;
    int m0 = blockIdx.x * 128, n0 = blockIdx.y * 64;
#pragma unroll
    for (int i = 0; i < 16; ++i) {               // stage X fp32 -> bf16 [m][k]
        int q = tid + i * 256, row = q >> 5, seg = q & 31;
        float4 v = *(const float4*)&X[(size_t)(m0 + row) * DIN + seg * 4];
        bf16* dst = &A_s[row * 136 + seg * 4];
        dst[0] = __float2bfloat16(v.x); dst[1] = __float2bfloat16(v.y);
        dst[2] = __float2bfloat16(v.z); dst[3] = __float2bfloat16(v.w);
    }
#pragma unroll
    for (int i = 0; i < 4; ++i) {                // stage Wet [n][k]
        int q = tid + i * 256, row = q >> 4, seg = q & 15;
        *(uint4*)&B_s[row * 136 + seg * 8] = *(const uint4*)&Wet[(size_t)(n0 + row) * DIN + seg * 8];
    }
    __syncthreads();
    f32x4 acc[2][4];
#pragma unroll
    for (int mt = 0; mt < 2; ++mt)
#pragma unroll
        for (int nt = 0; nt < 4; ++nt) acc[mt][nt] = (f32x4){0.f, 0.f, 0.f, 0.f};
#pragma unroll
    for (int ks = 0; ks < 4; ++ks) {
        bf16x8 a[2], b[4];
#pragma unroll
        for (int mt = 0; mt < 2; ++mt)
            a[mt] = *(const bf16x8*)&A_s[(wv * 32 + mt * 16 + fr) * 136 + ks * 32 + quad * 8];
#pragma unroll
        for (int nt = 0; nt < 4; ++nt)
            b[nt] = *(const bf16x8*)&B_s[(nt * 16 + fr) * 136 + ks * 32 + quad * 8];
#pragma unroll
        for (int mt = 0; mt < 2; ++mt)
#pragma unroll
            for (int nt = 0; nt < 4; ++nt)
                acc[mt][nt] = __builtin_amdgcn_mfma_f32_16x16x32_bf16(a[mt], b[nt], acc[mt][nt], 0, 0, 0);
    }
    __syncthreads();                             // B_s reuse as transpose bounce
#pragma unroll
    for (int mt = 0; mt < 2; ++mt)
#pragma unroll
        for (int nt = 0; nt < 4; ++nt) {
            int n = n0 + nt * 16 + fr;
            float bv = bias[n];
#pragma unroll
            for (int r = 0; r < 4; ++r) {
                int m = m0 + wv * 32 + mt * 16 + quad * 4 + r;
                float hv = acc[mt][nt][r] + bv;
                bf16 hb = __float2bfloat16(hv);
                H[(size_t)m * HDIM + n] = hb;
                B_s[(nt * 16 + fr) * 136 + (wv * 32 + mt * 16 + quad * 4 + r)] = hb;
            }
        }
    __syncthreads();
#pragma unroll
    for (int i = 0; i < 4; ++i) {                // coalesced Ut store [h][m]
        int q = tid + i * 256, row = q >> 4, seg = q & 15;
        *(uint4*)&Ut[(size_t)(n0 + row) * M_ROWS + m0 + seg * 8] = *(uint4*)&B_s[row * 136 + seg * 8];
    }
}

// ---------------- fused conv: E-MFMA + in-place in-LDS carry scan + T|M-MFMA + GELU ----------------
// LDS = 53.0 KB -> 3 blocks/CU
__global__ __launch_bounds__(256) void k_conv(const bf16* __restrict__ Ut,
                                              const bf16* __restrict__ Vg,
                                              const bf16* __restrict__ Mg,
                                              const float* __restrict__ Tdl,
                                              const float2* __restrict__ PA,
                                              const float* __restrict__ Dw,
                                              bf16* __restrict__ Yt) {
    __shared__ bf16 u_s[128 * 72];               // [bc][j]
    __shared__ bf16 A_s[64 * 136];               // [l][k2], k2<64: T, k2>=64: M
    __shared__ bf16 Eo_s[128 * 72];              // [bc][comp]: E, then carries, then o_s
    int h = blockIdx.x, bc0 = blockIdx.y * 128;
    int tid = threadIdx.x;
    int lane = tid & 63, wv = tid >> 6, quad = lane >> 4, fr = lane & 15;
    const float* Tdh = Tdl + (size_t)h * 66;
#pragma unroll
    for (int i = 0; i < 2; ++i) {                // stage M transposed into A_s cols 64..127
        int q = tid + i * 256, comp = q >> 3, seg = q & 7;
        uint4 v = *(const uint4*)&Mg[((size_t)h * 64 + comp) * 64 + seg * 8];
        const bf16* pv = (const bf16*)&v;
#pragma unroll
        for (int e = 0; e < 8; ++e) A_s[(seg * 8 + e) * 136 + 64 + comp] = pv[e];
    }
#pragma unroll
    for (int i = 0; i < 4; ++i) {                // stage u tile
        int q = tid + i * 256, row = q >> 3, c8 = q & 7;
        *(uint4*)&u_s[row * 72 + c8 * 8] =
            *(const uint4*)&Ut[(size_t)h * M_ROWS + (size_t)(bc0 + row) * 64 + c8 * 8];
    }
#pragma unroll
    for (int i = 0; i < 16; ++i) {               // Toeplitz T fill (Td direct from L2)
        int q = tid + i * 256, l = q >> 6, j = q & 63, d = l - j;
        A_s[l * 136 + j] = __float2bfloat16(d >= 0 ? Tdh[d] : 0.f);
    }
    __syncthreads();                             // u_s ready
    f32x4 eacc[4][2];
#pragma unroll
    for (int mt = 0; mt < 4; ++mt)
#pragma unroll
        for (int nf = 0; nf < 2; ++nf) eacc[mt][nf] = (f32x4){0.f, 0.f, 0.f, 0.f};
#pragma unroll
    for (int ks = 0; ks < 2; ++ks) {             // E-MFMA, V frags direct from global (L2-hot)
        bf16x8 a[4], b[2];
#pragma unroll
        for (int mt = 0; mt < 4; ++mt)
            a[mt] = *(const bf16x8*)&Vg[((size_t)h * 64 + mt * 16 + fr) * 64 + ks * 32 + quad * 8];
#pragma unroll
        for (int nf = 0; nf < 2; ++nf)
            b[nf] = *(const bf16x8*)&u_s[(wv * 32 + nf * 16 + fr) * 72 + ks * 32 + quad * 8];
#pragma unroll
        for (int mt = 0; mt < 4; ++mt)
#pragma unroll
            for (int nf = 0; nf < 2; ++nf)
                eacc[mt][nf] = __builtin_amdgcn_mfma_f32_16x16x32_bf16(a[mt], b[nf], eacc[mt][nf], 0, 0, 0);
    }
#pragma unroll
    for (int mt = 0; mt < 4; ++mt)               // E -> Eo_s [bc][comp], packed pairs
#pragma unroll
        for (int nf = 0; nf < 2; ++nf) {
            int bc = wv * 32 + nf * 16 + fr;
#pragma unroll
            for (int r = 0; r < 4; r += 2) {
                int comp = mt * 16 + quad * 4 + r;
                *(unsigned int*)&Eo_s[bc * 72 + comp] =
                    (unsigned int)f2bu(eacc[mt][nf][r]) | ((unsigned int)f2bu(eacc[mt][nf][r + 1]) << 16);
            }
        }
    __syncthreads();                             // Eo ready
    {                                            // in-place carry scan: thread = (b_local, n)
        int bl = tid >> 5, n = tid & 31;
        float2 a = PA[n * HDIM + h];
        float cr = 0.f, ci = 0.f;
#pragma unroll
        for (int c = 0; c < NCH; ++c) {
            int bc = bl * NCH + c;
            unsigned int* slot = (unsigned int*)&Eo_s[bc * 72 + 2 * n];
            unsigned int ev = *slot;
            *slot = (unsigned int)f2bu(cr) | ((unsigned int)f2bu(ci) << 16);
            float er = bu2f((unsigned short)(ev & 0xffff));
            float ei = bu2f((unsigned short)(ev >> 16));
            float nr = fmaf(a.x, cr, fmaf(-a.y, ci, er));
            ci = fmaf(a.x, ci, fmaf(a.y, cr, ei));
            cr = nr;
        }
    }
    __syncthreads();                             // carries in Eo_s
    f32x4 acc[4][2];
#pragma unroll
    for (int mt = 0; mt < 4; ++mt)
#pragma unroll
        for (int nf = 0; nf < 2; ++nf) acc[mt][nf] = (f32x4){0.f, 0.f, 0.f, 0.f};
#pragma unroll
    for (int ks = 0; ks < 4; ++ks) {
        bf16x8 a[4], b[2];
#pragma unroll
        for (int mt = 0; mt < 4; ++mt)
            a[mt] = *(const bf16x8*)&A_s[(mt * 16 + fr) * 136 + ks * 32 + quad * 8];
#pragma unroll
        for (int nf = 0; nf < 2; ++nf) {
            int row = (wv * 32 + nf * 16 + fr) * 72;
            b[nf] = (ks < 2) ? *(const bf16x8*)&u_s[row + ks * 32 + quad * 8]
                             : *(const bf16x8*)&Eo_s[row + (ks - 2) * 32 + quad * 8];
        }
#pragma unroll
        for (int mt = 0; mt < 4; ++mt)
#pragma unroll
            for (int nf = 0; nf < 2; ++nf)
                acc[mt][nf] = __builtin_amdgcn_mfma_f32_16x16x32_bf16(a[mt], b[nf], acc[mt][nf], 0, 0, 0);
    }
    float Dv = Dw[h];
    // epilogue writes target only this wave's own bc rows of Eo_s, after its carry reads
#pragma unroll
    for (int mt = 0; mt < 4; ++mt)
#pragma unroll
        for (int nf = 0; nf < 2; ++nf) {
            int bcl = wv * 32 + nf * 16 + fr;
#pragma unroll
            for (int r = 0; r < 4; ++r) {
                int l = mt * 16 + quad * 4 + r;
                float u = __bfloat162float(u_s[bcl * 72 + l]);
                float v = fmaf(Dv, u, acc[mt][nf][r]);
                float z2 = 1.5957691216057308f * (v + 0.044715f * v * v * v);
                Eo_s[bcl * 72 + l] = __float2bfloat16(v / (1.f + __expf(-z2)));
            }
        }
    __syncthreads();
#pragma unroll
    for (int i = 0; i < 4; ++i) {                // coalesced Yt store
        int q = tid + i * 256, row = q >> 3, c8 = q & 7;
        *(uint4*)&Yt[(size_t)h * M_ROWS + (size_t)(bc0 + row) * 64 + c8 * 8] =
            *(uint4*)&Eo_s[row * 72 + c8 * 8];
    }
}

// ---------------- output GEMM + GLU, reads Yt [h][m] directly (r15-proven swizzle) ----------------
__global__ __launch_bounds__(256) void k_glu2(const bf16* __restrict__ Yt,
                                              const bf16* __restrict__ Wt,
                                              const float* __restrict__ wb,
                                              bf16* __restrict__ G) {
    __shared__ bf16 A_s[128 * 72];               // [m][k-swizzled]
    __shared__ bf16 B1_s[64 * 72];
    __shared__ bf16 B2_s[64 * 72];
    int tid = threadIdx.x;
    int lane = tid & 63, wv = tid >> 6;
    int quad = lane >> 4, fr = lane & 15;
    int m0 = blockIdx.x * 128, n0 = blockIdx.y * 64;
    int mg = tid & 31, hg = tid >> 5;            // micro-tile coords: 32 m-groups x 8 h-groups
    f32x4 acc1[2][4], acc2[2][4];
#pragma unroll
    for (int mt = 0; mt < 2; ++mt)
#pragma unroll
        for (int nt = 0; nt < 4; ++nt) {
            acc1[mt][nt] = (f32x4){0.f,0.f,0.f,0.f};
            acc2[mt][nt] = (f32x4){0.f,0.f,0.f,0.f};
        }
    for (int kt = 0; kt < HDIM; kt += 64) {
        {                                        // A tile: 8 coalesced uint2 reads -> reg transpose
            uint2 rowv[8];
#pragma unroll
            for (int e = 0; e < 8; ++e)
                rowv[e] = *(const uint2*)&Yt[(size_t)(kt + hg * 8 + e) * M_ROWS + m0 + mg * 4];
#pragma unroll
            for (int j = 0; j < 4; ++j) {        // 4 swizzled uint4 writes
                unsigned int pk[4];
#pragma unroll
                for (int k2 = 0; k2 < 4; ++k2) {
                    unsigned int lo = ((const unsigned short*)&rowv[2 * k2])[j];
                    unsigned int hi = ((const unsigned short*)&rowv[2 * k2 + 1])[j];
                    pk[k2] = lo | (hi << 16);
                }
                int m = mg * 4 + j;
                int phys = hg ^ ((m >> 3) & 7);
                *(uint4*)&A_s[m * 72 + phys * 8] = *(uint4*)pk;
            }
        }
#pragma unroll
        for (int i = 0; i < 2; ++i) {
            int e = tid + i * 256, row = e >> 3, cm = e & 7;
            *(uint4*)&B1_s[row * 72 + cm * 8] =
                *(const uint4*)(Wt + (size_t)(n0 + row) * HDIM + kt + cm * 8);
            *(uint4*)&B2_s[row * 72 + cm * 8] =
                *(const uint4*)(Wt + (size_t)(256 + n0 + row) * HDIM + kt + cm * 8);
        }
        __syncthreads();
#pragma unroll
        for (int s = 0; s < 2; ++s) {
            bf16x8 a[2], b1[4], b2[4];
#pragma unroll
            for (int mt = 0; mt < 2; ++mt) {
                int ml = wv * 32 + mt * 16 + fr;
                int phys = (s * 4 + quad) ^ ((ml >> 3) & 7);
                a[mt] = *(const bf16x8*)&A_s[ml * 72 + phys * 8];
            }
#pragma unroll
            for (int nt = 0; nt < 4; ++nt) {
                b1[nt] = *(const bf16x8*)&B1_s[(nt * 16 + fr) * 72 + s * 32 + quad * 8];
                b2[nt] = *(const bf16x8*)&B2_s[(nt * 16 + fr) * 72 + s * 32 + quad * 8];
            }
#pragma unroll
            for (int mt = 0; mt < 2; ++mt)
#pragma unroll
                for (int nt = 0; nt < 4; ++nt) {
                    acc1[mt][nt] = __builtin_amdgcn_mfma_f32_16x16x32_bf16(a[mt], b1[nt], acc1[mt][nt], 0, 0, 0);
                    acc2[mt][nt] = __builtin_amdgcn_mfma_f32_16x16x32_bf16(a[mt], b2[nt], acc2[mt][nt], 0, 0, 0);
                }
        }
        __syncthreads();
    }
#pragma unroll
    for (int mt = 0; mt < 2; ++mt)
#pragma unroll
        for (int nt = 0; nt < 4; ++nt) {
            int n = n0 + nt * 16 + fr;
            float b1v = wb[n], b2v = wb[HDIM + n];
#pragma unroll
            for (int r = 0; r < 4; ++r) {
                int m = m0 + wv * 32 + mt * 16 + quad * 4 + r;
                float z1 = acc1[mt][nt][r] + b1v;
                float z2 = acc2[mt][nt][r] + b2v;
                G[(size_t)m * HDIM + n] = __float2bfloat16(z1 / (1.0f + __expf(-z2)));
            }
        }
}

// ---------------- residual + LayerNorm (bf16 H), 64-row tiles; mode 1: decoder ----------------
__global__ __launch_bounds__(256) void k_ln2(const bf16* __restrict__ G, bf16* __restrict__ Hb,
                                             const float* __restrict__ w, const float* __restrict__ bb,
                                             bf16* __restrict__ Ut,
                                             const float* __restrict__ dw,
                                             const float* __restrict__ db,
                                             float* __restrict__ outp, int mode) {
    __shared__ bf16 t_s[256][72];
    __shared__ float red[2][4][64];
    __shared__ float stat[2][64];
    __shared__ float w_s[256], b_s[256];
    __shared__ float dw_s[HDIM * DOUT];
    __shared__ float db_s[16];
    int m0 = blockIdx.x * 64;
    int tid = threadIdx.x;
    int r = tid & 63, qd = tid >> 6;
    w_s[tid] = w[tid]; b_s[tid] = bb[tid];
    if (mode == 1) {
        for (int e = tid; e < HDIM * DOUT; e += 256) dw_s[e] = dw[e];
        if (tid < DOUT) db_s[tid] = db[tid];
    }
    const bf16* Gp = G + (size_t)(m0 + r) * HDIM + qd * 64;
    bf16*       Hp = Hb + (size_t)(m0 + r) * HDIM + qd * 64;
    float rv[64];
    float sum = 0.f, sq = 0.f;
#pragma unroll
    for (int j = 0; j < 64; j += 8) {
        uint4 gv = *(const uint4*)&Gp[j];
        uint4 hv4 = *(const uint4*)&Hp[j];
        const bf16* gp = (const bf16*)&gv;
        const bf16* hp = (const bf16*)&hv4;
#pragma unroll
        for (int e = 0; e < 8; ++e) {
            float v = __bfloat162float(gp[e]) + __bfloat162float(hp[e]);
            rv[j + e] = v; sum += v; sq += v * v;
        }
    }
    red[0][qd][r] = sum; red[1][qd][r] = sq;
    __syncthreads();
    if (tid < 64) {
        float s  = red[0][0][tid] + red[0][1][tid] + red[0][2][tid] + red[0][3][tid];
        float s2 = red[1][0][tid] + red[1][1][tid] + red[1][2][tid] + red[1][3][tid];
        float mean = s * (1.f / HDIM);
        float var = s2 * (1.f / HDIM) - mean * mean;
        stat[0][tid] = mean; stat[1][tid] = rsqrtf(var + 1e-5f);
    }
    __syncthreads();
    float mean = stat[0][r], rstd = stat[1][r];
#pragma unroll
    for (int j = 0; j < 64; ++j)
        rv[j] = (rv[j] - mean) * rstd * w_s[qd * 64 + j] + b_s[qd * 64 + j];
    if (mode == 0) {
#pragma unroll
        for (int j = 0; j < 64; j += 8) {        // packed bf16 H write
            unsigned int pk[4];
#pragma unroll
            for (int e = 0; e < 4; ++e)
                pk[e] = (unsigned int)f2bu(rv[j + 2 * e]) | ((unsigned int)f2bu(rv[j + 2 * e + 1]) << 16);
            *(uint4*)&Hp[j] = *(uint4*)pk;
        }
    }
#pragma unroll
    for (int j = 0; j < 64; ++j) t_s[qd * 64 + j][r] = __float2bfloat16(rv[j]);
    __syncthreads();
    if (mode == 0) {
#pragma unroll
        for (int i = 0; i < 8; ++i) {            // coalesced Ut store: 256 h rows x 64 m
            int q = tid + i * 256, hh = q >> 3, seg = q & 7;
            *(uint4*)&Ut[(size_t)hh * M_ROWS + m0 + seg * 8] = *(uint4*)&t_s[hh][seg * 8];
        }
    } else {                                     // decoder from t_s
        for (int q = tid; q < 64 * DOUT; q += 256) {
            int ml = q / DOUT, o = q - ml * DOUT;
            float acc = db_s[o];
#pragma unroll 8
            for (int hh = 0; hh < HDIM; ++hh)
                acc = fmaf(__bfloat162float(t_s[hh][ml]), dw_s[hh * DOUT + o], acc);
            outp[(size_t)(m0 + ml) * DOUT + o] = acc;
        }
    }
}

extern "C" void kernel_launch(void* const* d_in, const int* in_sizes, int n_in,
                              void* d_out, int out_size, void* d_ws, size_t ws_size,
                              hipStream_t stream) {
    const float* x        = (const float*)d_in[0];
    const float* enc_w    = (const float*)d_in[1];
    const float* enc_b    = (const float*)d_in[2];
    const float* log_dt   = (const float*)d_in[3];
    const float* A_re_log = (const float*)d_in[4];
    const float* A_im     = (const float*)d_in[5];
    const float* B_re     = (const float*)d_in[6];
    const float* B_im     = (const float*)d_in[7];
    const float* C_re     = (const float*)d_in[8];
    const float* C_im     = (const float*)d_in[9];
    const float* Dp       = (const float*)d_in[10];
    const float* ln_w     = (const float*)d_in[11];
    const float* ln_b     = (const float*)d_in[12];
    const float* out_w    = (const float*)d_in[13];
    const float* out_b    = (const float*)d_in[14];
    const float* dec_w    = (const float*)d_in[15];
    const float* dec_b    = (const float*)d_in[16];
    float* outp = (float*)d_out;

    float* w = (float*)d_ws;
    const size_t PWE = (size_t)NLAYERS * NSTATE * HDIM;   // 32768
    const size_t MH  = (size_t)M_ROWS * HDIM;             // 8388608
    const size_t VME = (size_t)NLAYERS * HDIM * 64 * 64;  // 4M elems/matrix
    float2* PA64 = (float2*)(w + 4 * PWE);                // 256 KB
    float*  Td   = w + 6 * PWE;                           // 270 KB
    bf16*   Hbuf = (bf16*)(Td + (size_t)NLAYERS * HDIM * 66);  // 16.7 MB bf16
    bf16*   Ut   = Hbuf + MH;                             // 16.7 MB
    bf16*   Yt   = Ut + MH;                               // 16.7 MB
    bf16*   G    = Yt + MH;                               // 16.7 MB
    bf16*   Wt   = G + MH;                                // 1 MB
    bf16*   Wet  = Wt + (size_t)NLAYERS * 512 * HDIM;     // 64 KB
    bf16*   Vg   = Wet + (size_t)HDIM * DIN;              // 8 MB (all layers)
    bf16*   Mg   = Vg + VME;                              // 8 MB (all layers)

    {
        int total = VMB_ + TDB_ + PAB_ + WCB_ + HDIM * DIN / 256;
        k_setup<<<total, 256, 0, stream>>>(log_dt, A_re_log, A_im, B_re, B_im, C_re, C_im,
                                           out_w, enc_w, Td, Vg, Mg, PA64, Wt, Wet);
    }

    dim3 ge(M_ROWS / 128, HDIM / 64);
    k_enc2<<<ge, 256, 0, stream>>>(x, Wet, enc_b, Hbuf, Ut);

    dim3 gconv(HDIM, NBC / 128);
    dim3 gg(M_ROWS / 128, HDIM / 64);
    for (int layer = 0; layer < NLAYERS; ++layer) {
        const float2* pal = PA64 + (size_t)layer * NSTATE * HDIM;
        const float*  tdl = Td + (size_t)layer * HDIM * 66;
        const bf16*   vgl = Vg + (size_t)layer * HDIM * 64 * 64;
        const bf16*   mgl = Mg + (size_t)layer * HDIM * 64 * 64;
        k_conv<<<gconv, 256, 0, stream>>>(Ut, vgl, mgl, tdl, pal, Dp + layer * HDIM, Yt);
        k_glu2<<<gg, 256, 0, stream>>>(Yt, Wt + (size_t)layer * 512 * HDIM,
                                       out_b + layer * 2 * HDIM, G);
        k_ln2<<<M_ROWS / 64, 256, 0, stream>>>(G, Hbuf, ln_w + layer * HDIM,
                                               ln_b + layer * HDIM, Ut, dec_w, dec_b, outp,
                                               layer == NLAYERS - 1 ? 1 : 0);
    }
}

// Round 20
// 370.361 us; speedup vs baseline: 1.1005x; 1.0094x over previous
//
#include <hip/hip_runtime.h>
#include <hip/hip_bf16.h>
#include <math.h>

#define B_SZ    32
#define LSEQ    1024
#define DIN     128
#define HDIM    256
#define NLAYERS 4
#define NSTATE  32
#define DOUT    10
#define M_ROWS  (B_SZ*LSEQ)   // 32768
#define CH      64            // scan chunk length
#define NCH     (LSEQ/CH)     // 16 chunks
#define NBC     (B_SZ*NCH)    // 512 chunk-columns

typedef __hip_bfloat16 bf16;
typedef __attribute__((ext_vector_type(8))) short bf16x8;
typedef __attribute__((ext_vector_type(4))) float f32x4;

__device__ __forceinline__ unsigned short f2bu(float x) {
    bf16 b = __float2bfloat16(x);
    return *(unsigned short*)&b;
}
__device__ __forceinline__ float bu2f(unsigned short u) {
    bf16 b = *(bf16*)&u;
    return __bfloat162float(b);
}

// inline S4D discretization: returns (dtAre, dtAim, Wre, Wim)
__device__ __forceinline__ float4 s4param(const float* __restrict__ log_dt,
                                          const float* __restrict__ A_re_log,
                                          const float* __restrict__ A_im,
                                          const float* __restrict__ B_re,
                                          const float* __restrict__ B_im,
                                          const float* __restrict__ C_re,
                                          const float* __restrict__ C_im,
                                          int layer, int h, int n) {
    int hn = layer * HDIM + h;
    int idx = hn * NSTATE + n;
    float dt   = expf(log_dt[hn]);
    float Are  = -expf(A_re_log[idx]);
    float Aim  = A_im[idx];
    float dtAre = dt * Are, dtAim = dt * Aim;
    float ea   = expf(dtAre);
    float dAre = ea * cosf(dtAim), dAim = ea * sinf(dtAim);
    float nre = dAre - 1.0f, nim = dAim;
    float inv = 1.0f / (Are * Are + Aim * Aim);
    float tre = (nre * Are + nim * Aim) * inv;
    float tim = (nim * Are - nre * Aim) * inv;
    float Brv = B_re[idx], Biv = B_im[idx];
    float dBre = Brv * tre - Biv * tim;
    float dBim = Brv * tim + Biv * tre;
    float Crv = C_re[idx], Civ = C_im[idx];
    float Wre = Crv * dBre - Civ * dBim;
    float Wim = Crv * dBim + Civ * dBre;
    return make_float4(dtAre, dtAim, Wre, Wim);
}

// ---------------- ONE setup kernel: V/M, Td, PA64, weight transposes ----------------
#define VMB_ (NLAYERS*HDIM*64*32/256)    // 32768
#define TDB_ ((NLAYERS*HDIM*66+255)/256) // 264
#define PAB_ (NLAYERS*NSTATE*HDIM/256)   // 128
#define WCB_ (NLAYERS*512*256/256)       // 2048
__global__ void k_setup(const float* __restrict__ log_dt, const float* __restrict__ A_re_log,
                        const float* __restrict__ A_im, const float* __restrict__ B_re,
                        const float* __restrict__ B_im, const float* __restrict__ C_re,
                        const float* __restrict__ C_im, const float* __restrict__ out_w,
                        const float* __restrict__ enc_w, float* __restrict__ Td,
                        bf16* __restrict__ Vg, bf16* __restrict__ Mg,
                        float2* __restrict__ PA64, bf16* __restrict__ Wt,
                        bf16* __restrict__ Wet) {
    const float inv2pi = 0.15915494309189535f;
    const float twopi  = 6.283185307179586f;
    int bx = blockIdx.x;
    if (bx < VMB_) {                                 // V/M pair-elements
        int gid = bx * 256 + threadIdx.x;
        int jp = (gid & 31) * 2;
        int row = gid >> 5;                          // ((layer*256+h)*64)+comp
        int comp = row & 63, h = (row >> 6) & 255, layer = row >> 14;
        int n = comp >> 1, isIm = comp & 1;
        float4 q = s4param(log_dt, A_re_log, A_im, B_re, B_im, C_re, C_im, layer, h, n);
        unsigned int vpk = 0, mpk = 0;
#pragma unroll
        for (int e = 0; e < 2; ++e) {
            int j = jp + e;
            float dv = (float)(63 - j);
            float magv = __expf(dv * q.x);
            float pr = dv * q.y * inv2pi;
            float th = (pr - floorf(pr)) * twopi;
            float c = __cosf(th), s = __sinf(th);
            float vre = magv * (q.z * c - q.w * s);
            float vim = magv * (q.z * s + q.w * c);
            vpk |= (unsigned int)f2bu(isIm ? vim : vre) << (16 * e);
            float dm = (float)(j + 1);
            float magm = __expf(dm * q.x);
            float pr2 = dm * q.y * inv2pi;
            float th2 = (pr2 - floorf(pr2)) * twopi;
            float mv = isIm ? (-2.f * magm * __sinf(th2)) : (2.f * magm * __cosf(th2));
            mpk |= (unsigned int)f2bu(mv) << (16 * e);
        }
        ((unsigned int*)Vg)[(size_t)row * 32 + (jp >> 1)] = vpk;
        ((unsigned int*)Mg)[(size_t)row * 32 + (jp >> 1)] = mpk;
    } else if (bx < VMB_ + TDB_) {                   // Td
        int gid = (bx - VMB_) * 256 + threadIdx.x;
        int d = gid % 66;
        int lh = gid / 66;
        if (lh < NLAYERS * HDIM && d < 65) {
            int layer = lh >> 8, h = lh & 255;
            float fd = (float)d;
            float acc = 0.f;
            for (int n = 0; n < NSTATE; ++n) {
                float4 q = s4param(log_dt, A_re_log, A_im, B_re, B_im, C_re, C_im, layer, h, n);
                float mag = __expf(fd * q.x);
                float pr = fd * q.y * inv2pi;
                float th = (pr - floorf(pr)) * twopi;
                acc += mag * (q.z * __cosf(th) - q.w * __sinf(th));
            }
            Td[(size_t)lh * 66 + d] = 2.f * acc;
        }
    } else if (bx < VMB_ + TDB_ + PAB_) {            // PA64 = dA^64 per (layer,n,h)
        int idx = (bx - VMB_ - TDB_) * 256 + threadIdx.x;
        int h = idx & 255, n = (idx >> 8) & 31, layer = idx >> 13;
        float4 q = s4param(log_dt, A_re_log, A_im, B_re, B_im, C_re, C_im, layer, h, n);
        float e64 = expf(64.0f * q.x);
        float ph  = 64.0f * q.y;
        PA64[idx] = make_float2(e64 * cosf(ph), e64 * sinf(ph));
    } else if (bx < VMB_ + TDB_ + PAB_ + WCB_) {     // Wt transpose
        int idx = (bx - VMB_ - TDB_ - PAB_) * 256 + threadIdx.x;
        int k = idx & 255;
        int n = (idx >> 8) & 511;
        int layer = idx >> 17;
        Wt[idx] = __float2bfloat16(out_w[((size_t)(layer * 256 + k)) * 512 + n]);
    } else {                                         // Wet transpose
        int idx = (bx - VMB_ - TDB_ - PAB_ - WCB_) * 256 + threadIdx.x;
        int k = idx & 127, n = idx >> 7;
        Wet[idx] = __float2bfloat16(enc_w[(size_t)k * HDIM + n]);
    }
}

// ---------------- encoder GEMM (bf16 MFMA): H(bf16) = X@We + b, + transposed Ut ----------------
__global__ __launch_bounds__(256) void k_enc2(const float* __restrict__ X, const bf16* __restrict__ Wet,
                                              const float* __restrict__ bias, bf16* __restrict__ H,
                                              bf16* __restrict__ Ut) {
    __shared__ bf16 A_s[128 * 136];
    __shared__ bf16 B_s[64 * 136];
    int tid = threadIdx.x;
    int lane = tid & 63, wv = tid >> 6, quad = lane >> 4, fr = lane & 15;
    int m0 = blockIdx.x * 128, n0 = blockIdx.y * 64;
#pragma unroll
    for (int i = 0; i < 16; ++i) {               // stage X fp32 -> bf16 [m][k]
        int q = tid + i * 256, row = q >> 5, seg = q & 31;
        float4 v = *(const float4*)&X[(size_t)(m0 + row) * DIN + seg * 4];
        bf16* dst = &A_s[row * 136 + seg * 4];
        dst[0] = __float2bfloat16(v.x); dst[1] = __float2bfloat16(v.y);
        dst[2] = __float2bfloat16(v.z); dst[3] = __float2bfloat16(v.w);
    }
#pragma unroll
    for (int i = 0; i < 4; ++i) {                // stage Wet [n][k]
        int q = tid + i * 256, row = q >> 4, seg = q & 15;
        *(uint4*)&B_s[row * 136 + seg * 8] = *(const uint4*)&Wet[(size_t)(n0 + row) * DIN + seg * 8];
    }
    __syncthreads();
    f32x4 acc[2][4];
#pragma unroll
    for (int mt = 0; mt < 2; ++mt)
#pragma unroll
        for (int nt = 0; nt < 4; ++nt) acc[mt][nt] = (f32x4){0.f, 0.f, 0.f, 0.f};
#pragma unroll
    for (int ks = 0; ks < 4; ++ks) {
        bf16x8 a[2], b[4];
#pragma unroll
        for (int mt = 0; mt < 2; ++mt)
            a[mt] = *(const bf16x8*)&A_s[(wv * 32 + mt * 16 + fr) * 136 + ks * 32 + quad * 8];
#pragma unroll
        for (int nt = 0; nt < 4; ++nt)
            b[nt] = *(const bf16x8*)&B_s[(nt * 16 + fr) * 136 + ks * 32 + quad * 8];
#pragma unroll
        for (int mt = 0; mt < 2; ++mt)
#pragma unroll
            for (int nt = 0; nt < 4; ++nt)
                acc[mt][nt] = __builtin_amdgcn_mfma_f32_16x16x32_bf16(a[mt], b[nt], acc[mt][nt], 0, 0, 0);
    }
    __syncthreads();                             // B_s reuse as transpose bounce
#pragma unroll
    for (int mt = 0; mt < 2; ++mt)
#pragma unroll
        for (int nt = 0; nt < 4; ++nt) {
            int n = n0 + nt * 16 + fr;
            float bv = bias[n];
#pragma unroll
            for (int r = 0; r < 4; ++r) {
                int m = m0 + wv * 32 + mt * 16 + quad * 4 + r;
                float hv = acc[mt][nt][r] + bv;
                bf16 hb = __float2bfloat16(hv);
                H[(size_t)m * HDIM + n] = hb;
                B_s[(nt * 16 + fr) * 136 + (wv * 32 + mt * 16 + quad * 4 + r)] = hb;
            }
        }
    __syncthreads();
#pragma unroll
    for (int i = 0; i < 4; ++i) {                // coalesced Ut store [h][m]
        int q = tid + i * 256, row = q >> 4, seg = q & 15;
        *(uint4*)&Ut[(size_t)(n0 + row) * M_ROWS + m0 + seg * 8] = *(uint4*)&B_s[row * 136 + seg * 8];
    }
}

// ---------------- fused conv: u from global (L2-hot), LDS 35.8 KB -> 4 blocks/CU ----------------
__global__ __launch_bounds__(256) void k_conv(const bf16* __restrict__ Ut,
                                              const bf16* __restrict__ Vg,
                                              const bf16* __restrict__ Mg,
                                              const float* __restrict__ Tdl,
                                              const float2* __restrict__ PA,
                                              const float* __restrict__ Dw,
                                              bf16* __restrict__ Yt) {
    __shared__ bf16 A_s[64 * 136];               // [l][k2], k2<64: T, k2>=64: M
    __shared__ bf16 Eo_s[128 * 72];              // [bc][comp]: E, then carries, then o_s
    int h = blockIdx.x, bc0 = blockIdx.y * 128;
    int tid = threadIdx.x;
    int lane = tid & 63, wv = tid >> 6, quad = lane >> 4, fr = lane & 15;
    const float* Tdh = Tdl + (size_t)h * 66;
    const bf16* Uh = Ut + (size_t)h * M_ROWS + (size_t)bc0 * 64;
#pragma unroll
    for (int i = 0; i < 2; ++i) {                // stage M transposed into A_s cols 64..127
        int q = tid + i * 256, comp = q >> 3, seg = q & 7;
        uint4 v = *(const uint4*)&Mg[((size_t)h * 64 + comp) * 64 + seg * 8];
        const bf16* pv = (const bf16*)&v;
#pragma unroll
        for (int e = 0; e < 8; ++e) A_s[(seg * 8 + e) * 136 + 64 + comp] = pv[e];
    }
#pragma unroll
    for (int i = 0; i < 16; ++i) {               // Toeplitz T fill (Td direct from L2)
        int q = tid + i * 256, l = q >> 6, j = q & 63, d = l - j;
        A_s[l * 136 + j] = __float2bfloat16(d >= 0 ? Tdh[d] : 0.f);
    }
    f32x4 eacc[4][2];
#pragma unroll
    for (int mt = 0; mt < 4; ++mt)
#pragma unroll
        for (int nf = 0; nf < 2; ++nf) eacc[mt][nf] = (f32x4){0.f, 0.f, 0.f, 0.f};
#pragma unroll
    for (int ks = 0; ks < 2; ++ks) {             // E-MFMA, V and u frags direct from global
        bf16x8 a[4], b[2];
#pragma unroll
        for (int mt = 0; mt < 4; ++mt)
            a[mt] = *(const bf16x8*)&Vg[((size_t)h * 64 + mt * 16 + fr) * 64 + ks * 32 + quad * 8];
#pragma unroll
        for (int nf = 0; nf < 2; ++nf)
            b[nf] = *(const bf16x8*)&Uh[(size_t)(wv * 32 + nf * 16 + fr) * 64 + ks * 32 + quad * 8];
#pragma unroll
        for (int mt = 0; mt < 4; ++mt)
#pragma unroll
            for (int nf = 0; nf < 2; ++nf)
                eacc[mt][nf] = __builtin_amdgcn_mfma_f32_16x16x32_bf16(a[mt], b[nf], eacc[mt][nf], 0, 0, 0);
    }
#pragma unroll
    for (int mt = 0; mt < 4; ++mt)               // E -> Eo_s [bc][comp], packed pairs
#pragma unroll
        for (int nf = 0; nf < 2; ++nf) {
            int bc = wv * 32 + nf * 16 + fr;
#pragma unroll
            for (int r = 0; r < 4; r += 2) {
                int comp = mt * 16 + quad * 4 + r;
                *(unsigned int*)&Eo_s[bc * 72 + comp] =
                    (unsigned int)f2bu(eacc[mt][nf][r]) | ((unsigned int)f2bu(eacc[mt][nf][r + 1]) << 16);
            }
        }
    __syncthreads();                             // Eo + A_s ready
    {                                            // in-place carry scan: thread = (b_local, n)
        int bl = tid >> 5, n = tid & 31;
        float2 a = PA[n * HDIM + h];
        float cr = 0.f, ci = 0.f;
#pragma unroll
        for (int c = 0; c < NCH; ++c) {
            int bc = bl * NCH + c;
            unsigned int* slot = (unsigned int*)&Eo_s[bc * 72 + 2 * n];
            unsigned int ev = *slot;
            *slot = (unsigned int)f2bu(cr) | ((unsigned int)f2bu(ci) << 16);
            float er = bu2f((unsigned short)(ev & 0xffff));
            float ei = bu2f((unsigned short)(ev >> 16));
            float nr = fmaf(a.x, cr, fmaf(-a.y, ci, er));
            ci = fmaf(a.x, ci, fmaf(a.y, cr, ei));
            cr = nr;
        }
    }
    __syncthreads();                             // carries in Eo_s
    f32x4 acc[4][2];
#pragma unroll
    for (int mt = 0; mt < 4; ++mt)
#pragma unroll
        for (int nf = 0; nf < 2; ++nf) acc[mt][nf] = (f32x4){0.f, 0.f, 0.f, 0.f};
#pragma unroll
    for (int ks = 0; ks < 4; ++ks) {
        bf16x8 a[4], b[2];
#pragma unroll
        for (int mt = 0; mt < 4; ++mt)
            a[mt] = *(const bf16x8*)&A_s[(mt * 16 + fr) * 136 + ks * 32 + quad * 8];
#pragma unroll
        for (int nf = 0; nf < 2; ++nf) {
            int row = wv * 32 + nf * 16 + fr;
            b[nf] = (ks < 2) ? *(const bf16x8*)&Uh[(size_t)row * 64 + ks * 32 + quad * 8]
                             : *(const bf16x8*)&Eo_s[row * 72 + (ks - 2) * 32 + quad * 8];
        }
#pragma unroll
        for (int mt = 0; mt < 4; ++mt)
#pragma unroll
            for (int nf = 0; nf < 2; ++nf)
                acc[mt][nf] = __builtin_amdgcn_mfma_f32_16x16x32_bf16(a[mt], b[nf], acc[mt][nf], 0, 0, 0);
    }
    float Dv = Dw[h];
    // epilogue: u via uint2 gathers (L2-hot); writes only this wave's own Eo_s rows
#pragma unroll
    for (int mt = 0; mt < 4; ++mt)
#pragma unroll
        for (int nf = 0; nf < 2; ++nf) {
            int bcl = wv * 32 + nf * 16 + fr;
            uint2 uv = *(const uint2*)&Uh[(size_t)bcl * 64 + mt * 16 + quad * 4];
            const bf16* up = (const bf16*)&uv;
#pragma unroll
            for (int r = 0; r < 4; ++r) {
                int l = mt * 16 + quad * 4 + r;
                float u = __bfloat162float(up[r]);
                float v = fmaf(Dv, u, acc[mt][nf][r]);
                float z2 = 1.5957691216057308f * (v + 0.044715f * v * v * v);
                Eo_s[bcl * 72 + l] = __float2bfloat16(v / (1.f + __expf(-z2)));
            }
        }
    __syncthreads();
#pragma unroll
    for (int i = 0; i < 4; ++i) {                // coalesced Yt store
        int q = tid + i * 256, row = q >> 3, c8 = q & 7;
        *(uint4*)&Yt[(size_t)h * M_ROWS + (size_t)(bc0 + row) * 64 + c8 * 8] =
            *(uint4*)&Eo_s[row * 72 + c8 * 8];
    }
}

// ---------------- output GEMM + GLU, reads Yt [h][m] directly (r15-proven swizzle) ----------------
__global__ __launch_bounds__(256) void k_glu2(const bf16* __restrict__ Yt,
                                              const bf16* __restrict__ Wt,
                                              const float* __restrict__ wb,
                                              bf16* __restrict__ G) {
    __shared__ bf16 A_s[128 * 72];               // [m][k-swizzled]
    __shared__ bf16 B1_s[64 * 72];
    __shared__ bf16 B2_s[64 * 72];
    int tid = threadIdx.x;
    int lane = tid & 63, wv = tid >> 6;
    int quad = lane >> 4, fr = lane & 15;
    int m0 = blockIdx.x * 128, n0 = blockIdx.y * 64;
    int mg = tid & 31, hg = tid >> 5;            // micro-tile coords: 32 m-groups x 8 h-groups
    f32x4 acc1[2][4], acc2[2][4];
#pragma unroll
    for (int mt = 0; mt < 2; ++mt)
#pragma unroll
        for (int nt = 0; nt < 4; ++nt) {
            acc1[mt][nt] = (f32x4){0.f,0.f,0.f,0.f};
            acc2[mt][nt] = (f32x4){0.f,0.f,0.f,0.f};
        }
    for (int kt = 0; kt < HDIM; kt += 64) {
        {                                        // A tile: 8 coalesced uint2 reads -> reg transpose
            uint2 rowv[8];
#pragma unroll
            for (int e = 0; e < 8; ++e)
                rowv[e] = *(const uint2*)&Yt[(size_t)(kt + hg * 8 + e) * M_ROWS + m0 + mg * 4];
#pragma unroll
            for (int j = 0; j < 4; ++j) {        // 4 swizzled uint4 writes
                unsigned int pk[4];
#pragma unroll
                for (int k2 = 0; k2 < 4; ++k2) {
                    unsigned int lo = ((const unsigned short*)&rowv[2 * k2])[j];
                    unsigned int hi = ((const unsigned short*)&rowv[2 * k2 + 1])[j];
                    pk[k2] = lo | (hi << 16);
                }
                int m = mg * 4 + j;
                int phys = hg ^ ((m >> 3) & 7);
                *(uint4*)&A_s[m * 72 + phys * 8] = *(uint4*)pk;
            }
        }
#pragma unroll
        for (int i = 0; i < 2; ++i) {
            int e = tid + i * 256, row = e >> 3, cm = e & 7;
            *(uint4*)&B1_s[row * 72 + cm * 8] =
                *(const uint4*)(Wt + (size_t)(n0 + row) * HDIM + kt + cm * 8);
            *(uint4*)&B2_s[row * 72 + cm * 8] =
                *(const uint4*)(Wt + (size_t)(256 + n0 + row) * HDIM + kt + cm * 8);
        }
        __syncthreads();
#pragma unroll
        for (int s = 0; s < 2; ++s) {
            bf16x8 a[2], b1[4], b2[4];
#pragma unroll
            for (int mt = 0; mt < 2; ++mt) {
                int ml = wv * 32 + mt * 16 + fr;
                int phys = (s * 4 + quad) ^ ((ml >> 3) & 7);
                a[mt] = *(const bf16x8*)&A_s[ml * 72 + phys * 8];
            }
#pragma unroll
            for (int nt = 0; nt < 4; ++nt) {
                b1[nt] = *(const bf16x8*)&B1_s[(nt * 16 + fr) * 72 + s * 32 + quad * 8];
                b2[nt] = *(const bf16x8*)&B2_s[(nt * 16 + fr) * 72 + s * 32 + quad * 8];
            }
#pragma unroll
            for (int mt = 0; mt < 2; ++mt)
#pragma unroll
                for (int nt = 0; nt < 4; ++nt) {
                    acc1[mt][nt] = __builtin_amdgcn_mfma_f32_16x16x32_bf16(a[mt], b1[nt], acc1[mt][nt], 0, 0, 0);
                    acc2[mt][nt] = __builtin_amdgcn_mfma_f32_16x16x32_bf16(a[mt], b2[nt], acc2[mt][nt], 0, 0, 0);
                }
        }
        __syncthreads();
    }
#pragma unroll
    for (int mt = 0; mt < 2; ++mt)
#pragma unroll
        for (int nt = 0; nt < 4; ++nt) {
            int n = n0 + nt * 16 + fr;
            float b1v = wb[n], b2v = wb[HDIM + n];
#pragma unroll
            for (int r = 0; r < 4; ++r) {
                int m = m0 + wv * 32 + mt * 16 + quad * 4 + r;
                float z1 = acc1[mt][nt][r] + b1v;
                float z2 = acc2[mt][nt][r] + b2v;
                G[(size_t)m * HDIM + n] = __float2bfloat16(z1 / (1.0f + __expf(-z2)));
            }
        }
}

// ---------------- residual + LayerNorm (bf16 H), 64-row tiles; mode 1: decoder ----------------
__global__ __launch_bounds__(256) void k_ln2(const bf16* __restrict__ G, bf16* __restrict__ Hb,
                                             const float* __restrict__ w, const float* __restrict__ bb,
                                             bf16* __restrict__ Ut,
                                             const float* __restrict__ dw,
                                             const float* __restrict__ db,
                                             float* __restrict__ outp, int mode) {
    __shared__ bf16 t_s[256][72];
    __shared__ float red[2][4][64];
    __shared__ float stat[2][64];
    __shared__ float w_s[256], b_s[256];
    __shared__ float dw_s[HDIM * DOUT];
    __shared__ float db_s[16];
    int m0 = blockIdx.x * 64;
    int tid = threadIdx.x;
    int r = tid & 63, qd = tid >> 6;
    w_s[tid] = w[tid]; b_s[tid] = bb[tid];
    if (mode == 1) {
        for (int e = tid; e < HDIM * DOUT; e += 256) dw_s[e] = dw[e];
        if (tid < DOUT) db_s[tid] = db[tid];
    }
    const bf16* Gp = G + (size_t)(m0 + r) * HDIM + qd * 64;
    bf16*       Hp = Hb + (size_t)(m0 + r) * HDIM + qd * 64;
    float rv[64];
    float sum = 0.f, sq = 0.f;
#pragma unroll
    for (int j = 0; j < 64; j += 8) {
        uint4 gv = *(const uint4*)&Gp[j];
        uint4 hv4 = *(const uint4*)&Hp[j];
        const bf16* gp = (const bf16*)&gv;
        const bf16* hp = (const bf16*)&hv4;
#pragma unroll
        for (int e = 0; e < 8; ++e) {
            float v = __bfloat162float(gp[e]) + __bfloat162float(hp[e]);
            rv[j + e] = v; sum += v; sq += v * v;
        }
    }
    red[0][qd][r] = sum; red[1][qd][r] = sq;
    __syncthreads();
    if (tid < 64) {
        float s  = red[0][0][tid] + red[0][1][tid] + red[0][2][tid] + red[0][3][tid];
        float s2 = red[1][0][tid] + red[1][1][tid] + red[1][2][tid] + red[1][3][tid];
        float mean = s * (1.f / HDIM);
        float var = s2 * (1.f / HDIM) - mean * mean;
        stat[0][tid] = mean; stat[1][tid] = rsqrtf(var + 1e-5f);
    }
    __syncthreads();
    float mean = stat[0][r], rstd = stat[1][r];
#pragma unroll
    for (int j = 0; j < 64; ++j)
        rv[j] = (rv[j] - mean) * rstd * w_s[qd * 64 + j] + b_s[qd * 64 + j];
    if (mode == 0) {
#pragma unroll
        for (int j = 0; j < 64; j += 8) {        // packed bf16 H write
            unsigned int pk[4];
#pragma unroll
            for (int e = 0; e < 4; ++e)
                pk[e] = (unsigned int)f2bu(rv[j + 2 * e]) | ((unsigned int)f2bu(rv[j + 2 * e + 1]) << 16);
            *(uint4*)&Hp[j] = *(uint4*)pk;
        }
    }
#pragma unroll
    for (int j = 0; j < 64; ++j) t_s[qd * 64 + j][r] = __float2bfloat16(rv[j]);
    __syncthreads();
    if (mode == 0) {
#pragma unroll
        for (int i = 0; i < 8; ++i) {            // coalesced Ut store: 256 h rows x 64 m
            int q = tid + i * 256, hh = q >> 3, seg = q & 7;
            *(uint4*)&Ut[(size_t)hh * M_ROWS + m0 + seg * 8] = *(uint4*)&t_s[hh][seg * 8];
        }
    } else {                                     // decoder from t_s
        for (int q = tid; q < 64 * DOUT; q += 256) {
            int ml = q / DOUT, o = q - ml * DOUT;
            float acc = db_s[o];
#pragma unroll 8
            for (int hh = 0; hh < HDIM; ++hh)
                acc = fmaf(__bfloat162float(t_s[hh][ml]), dw_s[hh * DOUT + o], acc);
            outp[(size_t)(m0 + ml) * DOUT + o] = acc;
        }
    }
}

extern "C" void kernel_launch(void* const* d_in, const int* in_sizes, int n_in,
                              void* d_out, int out_size, void* d_ws, size_t ws_size,
                              hipStream_t stream) {
    const float* x        = (const float*)d_in[0];
    const float* enc_w    = (const float*)d_in[1];
    const float* enc_b    = (const float*)d_in[2];
    const float* log_dt   = (const float*)d_in[3];
    const float* A_re_log = (const float*)d_in[4];
    const float* A_im     = (const float*)d_in[5];
    const float* B_re     = (const float*)d_in[6];
    const float* B_im     = (const float*)d_in[7];
    const float* C_re     = (const float*)d_in[8];
    const float* C_im     = (const float*)d_in[9];
    const float* Dp       = (const float*)d_in[10];
    const float* ln_w     = (const float*)d_in[11];
    const float* ln_b     = (const float*)d_in[12];
    const float* out_w    = (const float*)d_in[13];
    const float* out_b    = (const float*)d_in[14];
    const float* dec_w    = (const float*)d_in[15];
    const float* dec_b    = (const float*)d_in[16];
    float* outp = (float*)d_out;

    float* w = (float*)d_ws;
    const size_t PWE = (size_t)NLAYERS * NSTATE * HDIM;   // 32768
    const size_t MH  = (size_t)M_ROWS * HDIM;             // 8388608
    const size_t VME = (size_t)NLAYERS * HDIM * 64 * 64;  // 4M elems/matrix
    float2* PA64 = (float2*)(w + 4 * PWE);                // 256 KB
    float*  Td   = w + 6 * PWE;                           // 270 KB
    bf16*   Hbuf = (bf16*)(Td + (size_t)NLAYERS * HDIM * 66);  // 16.7 MB bf16
    bf16*   Ut   = Hbuf + MH;                             // 16.7 MB
    bf16*   Yt   = Ut + MH;                               // 16.7 MB
    bf16*   G    = Yt + MH;                               // 16.7 MB
    bf16*   Wt   = G + MH;                                // 1 MB
    bf16*   Wet  = Wt + (size_t)NLAYERS * 512 * HDIM;     // 64 KB
    bf16*   Vg   = Wet + (size_t)HDIM * DIN;              // 8 MB (all layers)
    bf16*   Mg   = Vg + VME;                              // 8 MB (all layers)

    {
        int total = VMB_ + TDB_ + PAB_ + WCB_ + HDIM * DIN / 256;
        k_setup<<<total, 256, 0, stream>>>(log_dt, A_re_log, A_im, B_re, B_im, C_re, C_im,
                                           out_w, enc_w, Td, Vg, Mg, PA64, Wt, Wet);
    }

    dim3 ge(M_ROWS / 128, HDIM / 64);
    k_enc2<<<ge, 256, 0, stream>>>(x, Wet, enc_b, Hbuf, Ut);

    dim3 gconv(HDIM, NBC / 128);
    dim3 gg(M_ROWS / 128, HDIM / 64);
    for (int layer = 0; layer < NLAYERS; ++layer) {
        const float2* pal = PA64 + (size_t)layer * NSTATE * HDIM;
        const float*  tdl = Td + (size_t)layer * HDIM * 66;
        const bf16*   vgl = Vg + (size_t)layer * HDIM * 64 * 64;
        const bf16*   mgl = Mg + (size_t)layer * HDIM * 64 * 64;
        k_conv<<<gconv, 256, 0, stream>>>(Ut, vgl, mgl, tdl, pal, Dp + layer * HDIM, Yt);
        k_glu2<<<gg, 256, 0, stream>>>(Yt, Wt + (size_t)layer * 512 * HDIM,
                                       out_b + layer * 2 * HDIM, G);
        k_ln2<<<M_ROWS / 64, 256, 0, stream>>>(G, Hbuf, ln_w + layer * HDIM,
                                               ln_b + layer * HDIM, Ut, dec_w, dec_b, outp,
                                               layer == NLAYERS - 1 ? 1 : 0);
    }
}